// Round 1
// baseline (2632.071 us; speedup 1.0000x reference)
//
#include <hip/hip_runtime.h>
#include <math.h>

#define HW 4096
#define CC 96
#define DD 192
#define NS 16
#define KK 4

__device__ __forceinline__ float siluf(float x){ return x / (1.f + expf(-x)); }
__device__ __forceinline__ float softplusf(float x){ return (x > 20.f) ? x : log1pf(expf(x)); }

__device__ __forceinline__ int lmap_xs(int k, int l){
  if (k == 1) return ((l & 63) << 6) | (l >> 6);
  if (k == 2) return (HW - 1) - l;
  if (k == 3) { int r = (HW - 1) - l; return ((r & 63) << 6) | (r >> 6); }
  return l;
}

// K1: concat(rgb,t) -> conv3x3(192->96) + bias + BN + ReLU, NCHW out
__global__ void k_conv(const float* __restrict__ rgb, const float* __restrict__ tt,
                       const float* __restrict__ cw, const float* __restrict__ cb,
                       const float* __restrict__ bng, const float* __restrict__ bnb,
                       const float* __restrict__ bnm, const float* __restrict__ bnv,
                       float* __restrict__ out){
  int tid = blockIdx.x*256 + threadIdx.x;      // (b, co, pix), pix fast
  int pix = tid & (HW-1);
  int bc  = tid >> 12;
  int co  = bc % CC;
  int b   = bc / CC;
  int h = pix >> 6, w = pix & 63;
  float acc = 0.f;
  for (int ci = 0; ci < 2*CC; ++ci){
    const float* src = (ci < CC) ? (rgb + (size_t)(b*CC+ci)*HW)
                                 : (tt  + (size_t)(b*CC+ci-CC)*HW);
    const float* wp = cw + (size_t)(co*2*CC + ci)*9;
    #pragma unroll
    for (int dh = -1; dh <= 1; ++dh){
      int hh = h + dh;
      if (hh < 0 || hh > 63) continue;
      #pragma unroll
      for (int dw = -1; dw <= 1; ++dw){
        int ww = w + dw;
        if (ww < 0 || ww > 63) continue;
        acc += src[hh*64 + ww] * wp[(dh+1)*3 + (dw+1)];
      }
    }
  }
  acc += cb[co];
  acc = (acc - bnm[co]) * rsqrtf(bnv[co] + 1e-5f);
  acc = acc * bng[co] + bnb[co];
  out[tid] = fmaxf(acc, 0.f);
}

// K2a: per-pixel LayerNorm over C=96 -> xn (pixel-major, c contiguous)
__global__ void k_ln1(const float* __restrict__ conv, const float* __restrict__ g,
                      const float* __restrict__ be, float* __restrict__ xn){
  int tid = blockIdx.x*256 + threadIdx.x;   // b*HW + pix
  int b = tid >> 12; int pix = tid & (HW-1);
  const float* p = conv + (size_t)b*CC*HW + pix;
  float s = 0.f, s2 = 0.f;
  for (int c = 0; c < CC; ++c){ float v = p[(size_t)c*HW]; s += v; s2 += v*v; }
  float mu = s * (1.f/CC);
  float var = s2 * (1.f/CC) - mu*mu;
  float r = rsqrtf(var + 1e-5f);
  float* o = xn + (size_t)tid*CC;
  for (int c = 0; c < CC; ++c){
    float v = (p[(size_t)c*HW] - mu) * r;
    o[c] = v * g[c] + be[c];
  }
}

// K2b: xz(8192x384) = xn(8192x96) @ in_proj_w^T(96x384)
__global__ void k_inproj(const float* __restrict__ xn, const float* __restrict__ ipw,
                         float* __restrict__ xz){
  __shared__ float As[64][97];
  __shared__ __align__(16) float Bs[96][68];
  int p0 = blockIdx.x*64;
  int e0 = blockIdx.y*64;
  int tid = threadIdx.x;
  for (int idx = tid; idx < 64*96; idx += 256){
    int r = idx/96, c = idx - r*96;
    As[r][c] = xn[(size_t)(p0+r)*96 + c];
  }
  for (int idx = tid; idx < 96*64; idx += 256){
    int c = idx/64, e = idx - c*64;
    Bs[c][e] = ipw[(size_t)(e0+e)*96 + c];
  }
  __syncthreads();
  int tx = tid & 15, ty = tid >> 4;
  float acc[4][4] = {};
  for (int c = 0; c < 96; ++c){
    float a[4];
    #pragma unroll
    for (int i = 0; i < 4; ++i) a[i] = As[ty*4+i][c];
    float4 bb = *(const float4*)&Bs[c][tx*4];
    float bv[4] = {bb.x, bb.y, bb.z, bb.w};
    #pragma unroll
    for (int i = 0; i < 4; ++i)
      #pragma unroll
      for (int j = 0; j < 4; ++j) acc[i][j] += a[i]*bv[j];
  }
  for (int i = 0; i < 4; ++i){
    float4 o = {acc[i][0], acc[i][1], acc[i][2], acc[i][3]};
    *(float4*)&xz[(size_t)(p0+ty*4+i)*384 + e0 + tx*4] = o;
  }
}

// K3: depthwise 3x3 conv + bias + SiLU -> xc (B, L, 192)
__global__ void k_dwconv(const float* __restrict__ xz, const float* __restrict__ dww,
                         const float* __restrict__ dwb, float* __restrict__ xc){
  int tid = blockIdx.x*256 + threadIdx.x;   // ((b*HW+pix)*DD + d), d fast
  int d  = tid % DD;
  int bp = tid / DD;
  int pix = bp & (HW-1); int b = bp >> 12;
  int h = pix >> 6, w = pix & 63;
  float acc = dwb[d];
  #pragma unroll
  for (int dh = -1; dh <= 1; ++dh){
    int hh = h + dh;
    if (hh < 0 || hh > 63) continue;
    #pragma unroll
    for (int dw = -1; dw <= 1; ++dw){
      int ww = w + dw;
      if (ww < 0 || ww > 63) continue;
      acc += xz[((size_t)b*HW + hh*64 + ww)*384 + d] * dww[d*9 + (dh+1)*3 + (dw+1)];
    }
  }
  xc[(size_t)bp*DD + d] = siluf(acc);
}

// K4: x_dbl projections -> Bs(B,K,L,16), Cs(B,K,L,16), delta(B,K,L,192) (softplus applied)
__global__ void k_xdbl(const float* __restrict__ xc, const float* __restrict__ xpw,
                       const float* __restrict__ dtw, const float* __restrict__ dtb,
                       float* __restrict__ Bsb, float* __restrict__ Csb,
                       float* __restrict__ dlt){
  __shared__ float xs_t[8][194];
  __shared__ float wl[38*194];
  __shared__ float dts_t[8][38];
  int blk = blockIdx.x;
  int lc = blk & 511; int k = (blk >> 9) & 3; int b = blk >> 11;
  int l0 = lc*8;
  int tid = threadIdx.x;
  for (int idx = tid; idx < 38*192; idx += 256){
    int c = idx/192, d = idx - c*192;
    wl[c*194 + d] = xpw[(size_t)(k*38 + c)*192 + d];
  }
  for (int idx = tid; idx < 8*192; idx += 256){
    int li = idx/192, d = idx - li*192;
    int lm = lmap_xs(k, l0 + li);
    xs_t[li][d] = xc[((size_t)b*HW + lm)*DD + d];
  }
  __syncthreads();
  int b4k = b*KK + k;
  for (int o = tid; o < 8*38; o += 256){
    int li = o/38, c = o - li*38;
    const float* wrow = &wl[c*194];
    float s = 0.f;
    #pragma unroll 4
    for (int d = 0; d < 192; ++d) s += xs_t[li][d]*wrow[d];
    int l = l0 + li;
    if (c < 6)       dts_t[li][c] = s;
    else if (c < 22) Bsb[((size_t)b4k*HW + l)*NS + (c-6)]  = s;
    else             Csb[((size_t)b4k*HW + l)*NS + (c-22)] = s;
  }
  __syncthreads();
  for (int o = tid; o < 8*192; o += 256){
    int li = o/192, d = o - li*192;
    int l = l0 + li;
    float s = dtb[k*DD + d];
    #pragma unroll
    for (int r = 0; r < 6; ++r) s += dts_t[li][r]*dtw[(size_t)(k*DD+d)*6 + r];
    dlt[((size_t)b4k*HW + l)*DD + d] = softplusf(s);
  }
}

// K5: selective scan. 16 lanes = states, 16 chains(d) per block. ys (B,K,L,192)
__global__ void k_scan(const float* __restrict__ dlt, const float* __restrict__ xc,
                       const float* __restrict__ Bsb, const float* __restrict__ Csb,
                       const float* __restrict__ Alog, float* __restrict__ ys){
  int blk = blockIdx.x;                 // b*48 + k*12 + dblk
  int dblk = blk % 12; int k = (blk/12) % 4; int b = blk/48;
  int tid = threadIdx.x;
  int chain = tid >> 4, n = tid & 15;
  int d = dblk*16 + chain;
  int b4k = b*KK + k;
  float Av = -expf(Alog[(size_t)(k*DD + d)*NS + n]);
  const float* dp  = dlt + (size_t)b4k*HW*DD + d;
  const float* Bp  = Bsb + (size_t)b4k*HW*NS + n;
  const float* Cp  = Csb + (size_t)b4k*HW*NS + n;
  float*       yp  = ys  + (size_t)b4k*HW*DD + d;
  const float* xcb = xc  + (size_t)b*HW*DD + d;
  float h = 0.f;
  for (int l = 0; l < HW; ++l){
    float dv = dp[(size_t)l*DD];
    int lm = lmap_xs(k, l);
    float xv = xcb[(size_t)lm*DD];
    float Bv = Bp[(size_t)l*NS];
    float Cv = Cp[(size_t)l*NS];
    float e = __expf(dv*Av);
    h = h*e + dv*xv*Bv;
    float p = h*Cv;
    p += __shfl_xor(p, 1, 16);
    p += __shfl_xor(p, 2, 16);
    p += __shfl_xor(p, 4, 16);
    p += __shfl_xor(p, 8, 16);
    if (n == 0) yp[(size_t)l*DD] = p;
  }
}

// K6: merge 4 directions + D*xs skip, LN over 192, *silu(z), out_proj 192->96, NCHW out
__global__ void k_merge(const float* __restrict__ ys, const float* __restrict__ xc,
                        const float* __restrict__ Ds, const float* __restrict__ xz,
                        const float* __restrict__ ong, const float* __restrict__ onb,
                        const float* __restrict__ opw, float* __restrict__ out){
  __shared__ float yd[DD];
  __shared__ float rs[4], rs2[4];
  __shared__ float smu, srstd;
  int blk = blockIdx.x; int b = blk >> 12; int l = blk & (HW-1);
  int tid = threadIdx.x;
  int l1 = ((l & 63) << 6) | (l >> 6);
  size_t base = (size_t)b*KK*HW*DD;
  float s = 0.f, s2 = 0.f;
  if (tid < DD){
    int d = tid;
    float v;
    v  = ys[base + ((size_t)0*HW + l         )*DD + d];
    v += ys[base + ((size_t)1*HW + l1        )*DD + d];
    v += ys[base + ((size_t)2*HW + (HW-1-l ) )*DD + d];
    v += ys[base + ((size_t)3*HW + (HW-1-l1) )*DD + d];
    float xcv = xc[((size_t)b*HW + l)*DD + d];
    float dsum = Ds[d] + Ds[DD+d] + Ds[2*DD+d] + Ds[3*DD+d];
    v += xcv * dsum;
    yd[d] = v;
    s = v; s2 = v*v;
  }
  #pragma unroll
  for (int off = 32; off; off >>= 1){ s += __shfl_down(s, off); s2 += __shfl_down(s2, off); }
  if ((tid & 63) == 0){ rs[tid>>6] = s; rs2[tid>>6] = s2; }
  __syncthreads();
  if (tid == 0){
    float ts  = rs[0]+rs[1]+rs[2]+rs[3];
    float ts2 = rs2[0]+rs2[1]+rs2[2]+rs2[3];
    float mu = ts*(1.f/DD);
    float var = ts2*(1.f/DD) - mu*mu;
    smu = mu; srstd = rsqrtf(var + 1e-5f);
  }
  __syncthreads();
  if (tid < DD){
    float x = (yd[tid]-smu)*srstd*ong[tid] + onb[tid];
    float z = xz[((size_t)b*HW + l)*384 + DD + tid];
    yd[tid] = x * siluf(z);
  }
  __syncthreads();
  if (tid < CC){
    float acc = 0.f;
    const float* wr = opw + (size_t)tid*DD;
    #pragma unroll 4
    for (int d = 0; d < DD; ++d) acc += yd[d]*wr[d];
    out[((size_t)b*CC + tid)*HW + l] = acc;
  }
}

extern "C" void kernel_launch(void* const* d_in, const int* in_sizes, int n_in,
                              void* d_out, int out_size, void* d_ws, size_t ws_size,
                              hipStream_t stream) {
  const float* rgb   = (const float*)d_in[0];
  const float* tt    = (const float*)d_in[1];
  const float* cw    = (const float*)d_in[2];
  const float* cb    = (const float*)d_in[3];
  const float* bng   = (const float*)d_in[4];
  const float* bnb   = (const float*)d_in[5];
  const float* bnm   = (const float*)d_in[6];
  const float* bnv   = (const float*)d_in[7];
  const float* lng   = (const float*)d_in[8];
  const float* lnb   = (const float*)d_in[9];
  const float* ipw   = (const float*)d_in[10];
  const float* dww   = (const float*)d_in[11];
  const float* dwb   = (const float*)d_in[12];
  const float* xpw   = (const float*)d_in[13];
  const float* dtw   = (const float*)d_in[14];
  const float* dtb   = (const float*)d_in[15];
  const float* Alog  = (const float*)d_in[16];
  const float* Ds    = (const float*)d_in[17];
  const float* ong   = (const float*)d_in[18];
  const float* onb   = (const float*)d_in[19];
  const float* opw   = (const float*)d_in[20];
  float* out = (float*)d_out;

  float* ws = (float*)d_ws;
  float* conv = ws;                          // 786432
  float* xn   = ws + 786432;                 // 786432
  float* xz   = ws + 1572864;                // 3145728
  float* xc   = ws + 4718592;                // 1572864
  float* Bsb  = ws + 6291456;                // 524288
  float* Csb  = ws + 6815744;                // 524288
  float* dlt  = ws + 7340032;                // 6291456
  float* ysb  = ws + 13631488;               // 6291456  (end 19922944 floats ~76MB)

  k_conv<<<3072, 256, 0, stream>>>(rgb, tt, cw, cb, bng, bnb, bnm, bnv, conv);
  k_ln1<<<32, 256, 0, stream>>>(conv, lng, lnb, xn);
  dim3 g2(128, 6);
  k_inproj<<<g2, 256, 0, stream>>>(xn, ipw, xz);
  k_dwconv<<<6144, 256, 0, stream>>>(xz, dww, dwb, xc);
  k_xdbl<<<4096, 256, 0, stream>>>(xc, xpw, dtw, dtb, Bsb, Csb, dlt);
  k_scan<<<96, 256, 0, stream>>>(dlt, xc, Bsb, Csb, Alog, ysb);
  k_merge<<<8192, 256, 0, stream>>>(ysb, xc, Ds, xz, ong, onb, opw, out);
}

// Round 2
// 895.202 us; speedup vs baseline: 2.9402x; 2.9402x over previous
//
#include <hip/hip_runtime.h>
#include <math.h>

#define HW 4096
#define CC 96
#define DD 192
#define NS 16
#define KK 4
#define LC 64
#define NC 64
#define NCH (8*DD*NS)   // 24576 chains

__device__ __forceinline__ float siluf(float x){ return x / (1.f + expf(-x)); }
__device__ __forceinline__ float softplusf(float x){ return (x > 20.f) ? x : log1pf(expf(x)); }

__device__ __forceinline__ int lmap_xs(int k, int l){
  if (k == 1) return ((l & 63) << 6) | (l >> 6);
  if (k == 2) return (HW - 1) - l;
  if (k == 3) { int r = (HW - 1) - l; return ((r & 63) << 6) | (r >> 6); }
  return l;
}

// K1: concat(rgb,t) -> conv3x3(192->96) + bias + BN + ReLU, NCHW out
__global__ void k_conv(const float* __restrict__ rgb, const float* __restrict__ tt,
                       const float* __restrict__ cw, const float* __restrict__ cb,
                       const float* __restrict__ bng, const float* __restrict__ bnb,
                       const float* __restrict__ bnm, const float* __restrict__ bnv,
                       float* __restrict__ out){
  int tid = blockIdx.x*256 + threadIdx.x;      // (b, co, pix), pix fast
  int pix = tid & (HW-1);
  int bc  = tid >> 12;
  int co  = bc % CC;
  int b   = bc / CC;
  int h = pix >> 6, w = pix & 63;
  float acc = 0.f;
  for (int ci = 0; ci < 2*CC; ++ci){
    const float* src = (ci < CC) ? (rgb + (size_t)(b*CC+ci)*HW)
                                 : (tt  + (size_t)(b*CC+ci-CC)*HW);
    const float* wp = cw + (size_t)(co*2*CC + ci)*9;
    #pragma unroll
    for (int dh = -1; dh <= 1; ++dh){
      int hh = h + dh;
      if (hh < 0 || hh > 63) continue;
      #pragma unroll
      for (int dw = -1; dw <= 1; ++dw){
        int ww = w + dw;
        if (ww < 0 || ww > 63) continue;
        acc += src[hh*64 + ww] * wp[(dh+1)*3 + (dw+1)];
      }
    }
  }
  acc += cb[co];
  acc = (acc - bnm[co]) * rsqrtf(bnv[co] + 1e-5f);
  acc = acc * bng[co] + bnb[co];
  out[tid] = fmaxf(acc, 0.f);
}

// K2a: per-pixel LayerNorm over C=96 -> xn (pixel-major, c contiguous)
__global__ void k_ln1(const float* __restrict__ conv, const float* __restrict__ g,
                      const float* __restrict__ be, float* __restrict__ xn){
  int tid = blockIdx.x*256 + threadIdx.x;   // b*HW + pix
  int b = tid >> 12; int pix = tid & (HW-1);
  const float* p = conv + (size_t)b*CC*HW + pix;
  float s = 0.f, s2 = 0.f;
  for (int c = 0; c < CC; ++c){ float v = p[(size_t)c*HW]; s += v; s2 += v*v; }
  float mu = s * (1.f/CC);
  float var = s2 * (1.f/CC) - mu*mu;
  float r = rsqrtf(var + 1e-5f);
  float* o = xn + (size_t)tid*CC;
  for (int c = 0; c < CC; ++c){
    float v = (p[(size_t)c*HW] - mu) * r;
    o[c] = v * g[c] + be[c];
  }
}

// K2b: xz(8192x384) = xn(8192x96) @ in_proj_w^T(96x384)
__global__ void k_inproj(const float* __restrict__ xn, const float* __restrict__ ipw,
                         float* __restrict__ xz){
  __shared__ float As[64][97];
  __shared__ __align__(16) float Bs[96][68];
  int p0 = blockIdx.x*64;
  int e0 = blockIdx.y*64;
  int tid = threadIdx.x;
  for (int idx = tid; idx < 64*96; idx += 256){
    int r = idx/96, c = idx - r*96;
    As[r][c] = xn[(size_t)(p0+r)*96 + c];
  }
  for (int idx = tid; idx < 96*64; idx += 256){
    int c = idx/64, e = idx - c*64;
    Bs[c][e] = ipw[(size_t)(e0+e)*96 + c];
  }
  __syncthreads();
  int tx = tid & 15, ty = tid >> 4;
  float acc[4][4] = {};
  for (int c = 0; c < 96; ++c){
    float a[4];
    #pragma unroll
    for (int i = 0; i < 4; ++i) a[i] = As[ty*4+i][c];
    float4 bb = *(const float4*)&Bs[c][tx*4];
    float bv[4] = {bb.x, bb.y, bb.z, bb.w};
    #pragma unroll
    for (int i = 0; i < 4; ++i)
      #pragma unroll
      for (int j = 0; j < 4; ++j) acc[i][j] += a[i]*bv[j];
  }
  for (int i = 0; i < 4; ++i){
    float4 o = {acc[i][0], acc[i][1], acc[i][2], acc[i][3]};
    *(float4*)&xz[(size_t)(p0+ty*4+i)*384 + e0 + tx*4] = o;
  }
}

// K3: depthwise 3x3 conv + bias + SiLU -> xc (B, L, 192)
__global__ void k_dwconv(const float* __restrict__ xz, const float* __restrict__ dww,
                         const float* __restrict__ dwb, float* __restrict__ xc){
  int tid = blockIdx.x*256 + threadIdx.x;   // ((b*HW+pix)*DD + d), d fast
  int d  = tid % DD;
  int bp = tid / DD;
  int pix = bp & (HW-1); int b = bp >> 12;
  int h = pix >> 6, w = pix & 63;
  float acc = dwb[d];
  #pragma unroll
  for (int dh = -1; dh <= 1; ++dh){
    int hh = h + dh;
    if (hh < 0 || hh > 63) continue;
    #pragma unroll
    for (int dw = -1; dw <= 1; ++dw){
      int ww = w + dw;
      if (ww < 0 || ww > 63) continue;
      acc += xz[((size_t)b*HW + hh*64 + ww)*384 + d] * dww[d*9 + (dh+1)*3 + (dw+1)];
    }
  }
  xc[(size_t)bp*DD + d] = siluf(acc);
}

// K4: x_dbl projections -> Bs(B,K,L,16), Cs(B,K,L,16), delta(B,K,L,192) (softplus applied)
__global__ void k_xdbl(const float* __restrict__ xc, const float* __restrict__ xpw,
                       const float* __restrict__ dtw, const float* __restrict__ dtb,
                       float* __restrict__ Bsb, float* __restrict__ Csb,
                       float* __restrict__ dlt){
  __shared__ float xs_t[8][194];
  __shared__ float wl[38*194];
  __shared__ float dts_t[8][38];
  int blk = blockIdx.x;
  int lc = blk & 511; int k = (blk >> 9) & 3; int b = blk >> 11;
  int l0 = lc*8;
  int tid = threadIdx.x;
  for (int idx = tid; idx < 38*192; idx += 256){
    int c = idx/192, d = idx - c*192;
    wl[c*194 + d] = xpw[(size_t)(k*38 + c)*192 + d];
  }
  for (int idx = tid; idx < 8*192; idx += 256){
    int li = idx/192, d = idx - li*192;
    int lm = lmap_xs(k, l0 + li);
    xs_t[li][d] = xc[((size_t)b*HW + lm)*DD + d];
  }
  __syncthreads();
  int b4k = b*KK + k;
  for (int o = tid; o < 8*38; o += 256){
    int li = o/38, c = o - li*38;
    const float* wrow = &wl[c*194];
    float s = 0.f;
    #pragma unroll 4
    for (int d = 0; d < 192; ++d) s += xs_t[li][d]*wrow[d];
    int l = l0 + li;
    if (c < 6)       dts_t[li][c] = s;
    else if (c < 22) Bsb[((size_t)b4k*HW + l)*NS + (c-6)]  = s;
    else             Csb[((size_t)b4k*HW + l)*NS + (c-22)] = s;
  }
  __syncthreads();
  for (int o = tid; o < 8*192; o += 256){
    int li = o/192, d = o - li*192;
    int l = l0 + li;
    float s = dtb[k*DD + d];
    #pragma unroll
    for (int r = 0; r < 6; ++r) s += dts_t[li][r]*dtw[(size_t)(k*DD+d)*6 + r];
    dlt[((size_t)b4k*HW + l)*DD + d] = softplusf(s);
  }
}

// K5a: per-chunk scan summaries. Thread owns (b4k, chunk, d), all 16 states in regs.
// Ac/Bc layout: [chunk][chain], chain = (b4k*DD+d)*NS + n.
__global__ void k_scan1(const float* __restrict__ dlt, const float* __restrict__ xc,
                        const float* __restrict__ Bsb, const float* __restrict__ Alog,
                        float* __restrict__ Ac, float* __restrict__ Bc){
  int tid = blockIdx.x*256 + threadIdx.x;   // ((b4k*NC + chunk)*DD + d)
  int d = tid % DD;
  int rest = tid / DD;
  int chunk = rest & (NC-1);
  int b4k = rest >> 6;
  int k = b4k & 3, b = b4k >> 2;
  float Av[NS], h[NS], ap[NS];
  #pragma unroll
  for (int n = 0; n < NS; ++n){
    Av[n] = -expf(Alog[(size_t)(k*DD+d)*NS + n]);
    h[n] = 0.f; ap[n] = 1.f;
  }
  int l0 = chunk*LC;
  const float* dp  = dlt + ((size_t)b4k*HW + l0)*DD + d;
  const float* Bp  = Bsb + ((size_t)b4k*HW + l0)*NS;
  const float* xcb = xc  + (size_t)b*HW*DD + d;
  for (int i = 0; i < LC; ++i){
    float dv = dp[(size_t)i*DD];
    int lm = lmap_xs(k, l0 + i);
    float du = dv * xcb[(size_t)lm*DD];
    const float4* B4 = (const float4*)&Bp[i*NS];
    float4 b0 = B4[0], b1 = B4[1], b2 = B4[2], b3 = B4[3];
    float Bv[NS] = {b0.x,b0.y,b0.z,b0.w, b1.x,b1.y,b1.z,b1.w,
                    b2.x,b2.y,b2.z,b2.w, b3.x,b3.y,b3.z,b3.w};
    #pragma unroll
    for (int n = 0; n < NS; ++n){
      float a = __expf(dv*Av[n]);
      h[n] = h[n]*a + du*Bv[n];
      ap[n] *= a;
    }
  }
  size_t base = (size_t)chunk*NCH + (size_t)(b4k*DD + d)*NS;
  #pragma unroll
  for (int n = 0; n < NS; n += 4){
    *(float4*)&Ac[base+n] = make_float4(ap[n],ap[n+1],ap[n+2],ap[n+3]);
    *(float4*)&Bc[base+n] = make_float4(h[n],h[n+1],h[n+2],h[n+3]);
  }
}

// K5b: sequential prefix over chunk summaries. One thread per chain.
__global__ void k_scan2(const float* __restrict__ Ac, const float* __restrict__ Bc,
                        float* __restrict__ hst){
  int chain = blockIdx.x*256 + threadIdx.x;
  float h = 0.f;
  for (int c = 0; c < NC; ++c){
    size_t idx = (size_t)c*NCH + chain;
    hst[idx] = h;
    h = Ac[idx]*h + Bc[idx];
  }
}

// K5c: re-run chunks with correct h0, emit ys (B,K,L,192)
__global__ void k_scan3(const float* __restrict__ dlt, const float* __restrict__ xc,
                        const float* __restrict__ Bsb, const float* __restrict__ Csb,
                        const float* __restrict__ Alog, const float* __restrict__ hst,
                        float* __restrict__ ys){
  int tid = blockIdx.x*256 + threadIdx.x;
  int d = tid % DD;
  int rest = tid / DD;
  int chunk = rest & (NC-1);
  int b4k = rest >> 6;
  int k = b4k & 3, b = b4k >> 2;
  float Av[NS], h[NS];
  size_t hbase = (size_t)chunk*NCH + (size_t)(b4k*DD + d)*NS;
  #pragma unroll
  for (int n = 0; n < NS; ++n){
    Av[n] = -expf(Alog[(size_t)(k*DD+d)*NS + n]);
    h[n] = hst[hbase + n];
  }
  int l0 = chunk*LC;
  const float* dp  = dlt + ((size_t)b4k*HW + l0)*DD + d;
  const float* Bp  = Bsb + ((size_t)b4k*HW + l0)*NS;
  const float* Cp  = Csb + ((size_t)b4k*HW + l0)*NS;
  const float* xcb = xc  + (size_t)b*HW*DD + d;
  float* yp = ys + ((size_t)b4k*HW + l0)*DD + d;
  for (int i = 0; i < LC; ++i){
    float dv = dp[(size_t)i*DD];
    int lm = lmap_xs(k, l0 + i);
    float du = dv * xcb[(size_t)lm*DD];
    const float4* B4 = (const float4*)&Bp[i*NS];
    float4 b0 = B4[0], b1 = B4[1], b2 = B4[2], b3 = B4[3];
    float Bv[NS] = {b0.x,b0.y,b0.z,b0.w, b1.x,b1.y,b1.z,b1.w,
                    b2.x,b2.y,b2.z,b2.w, b3.x,b3.y,b3.z,b3.w};
    const float4* C4 = (const float4*)&Cp[i*NS];
    float4 c0 = C4[0], c1 = C4[1], c2 = C4[2], c3 = C4[3];
    float Cv[NS] = {c0.x,c0.y,c0.z,c0.w, c1.x,c1.y,c1.z,c1.w,
                    c2.x,c2.y,c2.z,c2.w, c3.x,c3.y,c3.z,c3.w};
    float y = 0.f;
    #pragma unroll
    for (int n = 0; n < NS; ++n){
      float a = __expf(dv*Av[n]);
      h[n] = h[n]*a + du*Bv[n];
      y += h[n]*Cv[n];
    }
    yp[(size_t)i*DD] = y;
  }
}

// K6: merge 4 directions + D*xs skip, LN over 192, *silu(z), out_proj 192->96, NCHW out
__global__ void k_merge(const float* __restrict__ ys, const float* __restrict__ xc,
                        const float* __restrict__ Ds, const float* __restrict__ xz,
                        const float* __restrict__ ong, const float* __restrict__ onb,
                        const float* __restrict__ opw, float* __restrict__ out){
  __shared__ float yd[DD];
  __shared__ float rs[4], rs2[4];
  __shared__ float smu, srstd;
  int blk = blockIdx.x; int b = blk >> 12; int l = blk & (HW-1);
  int tid = threadIdx.x;
  int l1 = ((l & 63) << 6) | (l >> 6);
  size_t base = (size_t)b*KK*HW*DD;
  float s = 0.f, s2 = 0.f;
  if (tid < DD){
    int d = tid;
    float v;
    v  = ys[base + ((size_t)0*HW + l         )*DD + d];
    v += ys[base + ((size_t)1*HW + l1        )*DD + d];
    v += ys[base + ((size_t)2*HW + (HW-1-l ) )*DD + d];
    v += ys[base + ((size_t)3*HW + (HW-1-l1) )*DD + d];
    float xcv = xc[((size_t)b*HW + l)*DD + d];
    float dsum = Ds[d] + Ds[DD+d] + Ds[2*DD+d] + Ds[3*DD+d];
    v += xcv * dsum;
    yd[d] = v;
    s = v; s2 = v*v;
  }
  #pragma unroll
  for (int off = 32; off; off >>= 1){ s += __shfl_down(s, off); s2 += __shfl_down(s2, off); }
  if ((tid & 63) == 0){ rs[tid>>6] = s; rs2[tid>>6] = s2; }
  __syncthreads();
  if (tid == 0){
    float ts  = rs[0]+rs[1]+rs[2]+rs[3];
    float ts2 = rs2[0]+rs2[1]+rs2[2]+rs2[3];
    float mu = ts*(1.f/DD);
    float var = ts2*(1.f/DD) - mu*mu;
    smu = mu; srstd = rsqrtf(var + 1e-5f);
  }
  __syncthreads();
  if (tid < DD){
    float x = (yd[tid]-smu)*srstd*ong[tid] + onb[tid];
    float z = xz[((size_t)b*HW + l)*384 + DD + tid];
    yd[tid] = x * siluf(z);
  }
  __syncthreads();
  if (tid < CC){
    float acc = 0.f;
    const float* wr = opw + (size_t)tid*DD;
    #pragma unroll 4
    for (int d = 0; d < DD; ++d) acc += yd[d]*wr[d];
    out[((size_t)b*CC + tid)*HW + l] = acc;
  }
}

extern "C" void kernel_launch(void* const* d_in, const int* in_sizes, int n_in,
                              void* d_out, int out_size, void* d_ws, size_t ws_size,
                              hipStream_t stream) {
  const float* rgb   = (const float*)d_in[0];
  const float* tt    = (const float*)d_in[1];
  const float* cw    = (const float*)d_in[2];
  const float* cb    = (const float*)d_in[3];
  const float* bng   = (const float*)d_in[4];
  const float* bnb   = (const float*)d_in[5];
  const float* bnm   = (const float*)d_in[6];
  const float* bnv   = (const float*)d_in[7];
  const float* lng   = (const float*)d_in[8];
  const float* lnb   = (const float*)d_in[9];
  const float* ipw   = (const float*)d_in[10];
  const float* dww   = (const float*)d_in[11];
  const float* dwb   = (const float*)d_in[12];
  const float* xpw   = (const float*)d_in[13];
  const float* dtw   = (const float*)d_in[14];
  const float* dtb   = (const float*)d_in[15];
  const float* Alog  = (const float*)d_in[16];
  const float* Ds    = (const float*)d_in[17];
  const float* ong   = (const float*)d_in[18];
  const float* onb   = (const float*)d_in[19];
  const float* opw   = (const float*)d_in[20];
  float* out = (float*)d_out;

  float* ws = (float*)d_ws;
  float* conv = ws;                          // 786432
  float* xn   = ws + 786432;                 // 786432
  float* xz   = ws + 1572864;                // 3145728
  float* xc   = ws + 4718592;                // 1572864
  float* Bsb  = ws + 6291456;                // 524288
  float* Csb  = ws + 6815744;                // 524288
  float* dlt  = ws + 7340032;                // 6291456
  float* ysb  = ws + 13631488;               // 6291456  (end 19922944 floats ~76MB)
  // scan scratch (reuses dead regions):
  float* Ac   = ysb;                         // 64*24576 = 1572864 (dead after k_scan2)
  float* Bc   = ysb + 1572864;               // 1572864 (dead after k_scan2)
  float* hst  = ws;                          // 1572864 (conv+xn region, dead after k_inproj)

  k_conv<<<3072, 256, 0, stream>>>(rgb, tt, cw, cb, bng, bnb, bnm, bnv, conv);
  k_ln1<<<32, 256, 0, stream>>>(conv, lng, lnb, xn);
  dim3 g2(128, 6);
  k_inproj<<<g2, 256, 0, stream>>>(xn, ipw, xz);
  k_dwconv<<<6144, 256, 0, stream>>>(xz, dww, dwb, xc);
  k_xdbl<<<4096, 256, 0, stream>>>(xc, xpw, dtw, dtb, Bsb, Csb, dlt);
  k_scan1<<<384, 256, 0, stream>>>(dlt, xc, Bsb, Alog, Ac, Bc);
  k_scan2<<<96, 256, 0, stream>>>(Ac, Bc, hst);
  k_scan3<<<384, 256, 0, stream>>>(dlt, xc, Bsb, Csb, Alog, hst, ysb);
  k_merge<<<8192, 256, 0, stream>>>(ysb, xc, Ds, xz, ong, onb, opw, out);
}

// Round 3
// 492.690 us; speedup vs baseline: 5.3422x; 1.8170x over previous
//
#include <hip/hip_runtime.h>
#include <math.h>

#define HW 4096
#define CC 96
#define DD 192
#define NS 16
#define KK 4
#define LC 64
#define NC 64
#define NCH (8*DD*NS)   // 24576 chains

__device__ __forceinline__ float siluf(float x){ return x / (1.f + expf(-x)); }
__device__ __forceinline__ float softplusf(float x){ return (x > 20.f) ? x : log1pf(expf(x)); }

__device__ __forceinline__ int lmap_xs(int k, int l){
  if (k == 1) return ((l & 63) << 6) | (l >> 6);
  if (k == 2) return (HW - 1) - l;
  if (k == 3) { int r = (HW - 1) - l; return ((r & 63) << 6) | (r >> 6); }
  return l;
}

// K1: conv3x3(192->96) partials, K-split over ci.
// Block: 512 thr = 48co x 512pix(8 rows), K-chunk 24ci (3 stages of 8).
// Thread: 6co x 8px register tile. Grid: 8kc x 2cog x 2b x 8pt = 256 blocks.
// pbuf layout: [kc][b][pix][co96]
__global__ void __launch_bounds__(512, 2)
k_conv1(const float* __restrict__ rgb, const float* __restrict__ tt,
        const float* __restrict__ cw, float* __restrict__ pbuf){
  __shared__ float in_lds[8][10][68];
  __shared__ float w_lds[8][9][48];
  int bi = blockIdx.x;
  int kc  = bi & 7;        int ci0 = kc*24;
  int r2  = bi >> 3;
  int cog = r2 & 1;        int co0 = cog*48;
  int r3  = r2 >> 1;
  int b   = r3 & 1;
  int pt  = r3 >> 1;       int h0 = pt*8;
  int tid = threadIdx.x;
  int pg = tid & 63;  int r = pg >> 3;  int w0 = (pg & 7)*8;
  int cg = tid >> 6;  int co_t = cg*6;

  float acc[6][8];
  #pragma unroll
  for (int c = 0; c < 6; ++c)
    #pragma unroll
    for (int p = 0; p < 8; ++p) acc[c][p] = 0.f;

  for (int s = 0; s < 3; ++s){
    if (s) __syncthreads();
    // zero halo columns
    for (int i = tid; i < 80; i += 512){ in_lds[i/10][i%10][0] = 0.f; in_lds[i/10][i%10][65] = 0.f; }
    // stage input 8ci x 10rows x 64
    for (int i = tid; i < 5120; i += 512){
      int ci = i / 640; int rr = (i % 640) / 64; int w = i & 63;
      int grow = h0 - 1 + rr;
      int cig = ci0 + s*8 + ci;
      float v = 0.f;
      if (grow >= 0 && grow < 64){
        const float* src = (cig < CC) ? (rgb + (size_t)(b*CC+cig)*HW)
                                      : (tt  + (size_t)(b*CC+cig-CC)*HW);
        v = src[grow*64 + w];
      }
      in_lds[ci][rr][w+1] = v;
    }
    // stage weights 8ci x 9tap x 48co (transposed)
    for (int i = tid; i < 3456; i += 512){
      int co = i % 48; int rest = i / 48; int ci = rest / 9; int tap = rest % 9;
      int cig = ci0 + s*8 + ci;
      w_lds[ci][tap][co] = cw[((size_t)(co0+co)*192 + cig)*9 + tap];
    }
    __syncthreads();
    #pragma unroll
    for (int ci = 0; ci < 8; ++ci){
      float rowv[3][10];
      #pragma unroll
      for (int rr = 0; rr < 3; ++rr){
        const float* rp = &in_lds[ci][r+rr][w0];
        float4 a = *(const float4*)rp;
        float4 bb = *(const float4*)(rp+4);
        float2 cc = *(const float2*)(rp+8);
        rowv[rr][0]=a.x; rowv[rr][1]=a.y; rowv[rr][2]=a.z; rowv[rr][3]=a.w;
        rowv[rr][4]=bb.x; rowv[rr][5]=bb.y; rowv[rr][6]=bb.z; rowv[rr][7]=bb.w;
        rowv[rr][8]=cc.x; rowv[rr][9]=cc.y;
      }
      #pragma unroll
      for (int tap = 0; tap < 9; ++tap){
        int rt = tap/3, ct = tap - rt*3;
        float2 wa = *(const float2*)&w_lds[ci][tap][co_t];
        float2 wb = *(const float2*)&w_lds[ci][tap][co_t+2];
        float2 wc = *(const float2*)&w_lds[ci][tap][co_t+4];
        float wv[6] = {wa.x, wa.y, wb.x, wb.y, wc.x, wc.y};
        #pragma unroll
        for (int p = 0; p < 8; ++p){
          float iv = rowv[rt][p + ct];
          #pragma unroll
          for (int c = 0; c < 6; ++c) acc[c][p] += wv[c]*iv;
        }
      }
    }
  }
  // write partials
  #pragma unroll
  for (int p = 0; p < 8; ++p){
    int pix = (h0 + r)*64 + w0 + p;
    float* o = pbuf + (((size_t)kc*2 + b)*HW + pix)*CC + co0 + co_t;
    float2 o0 = {acc[0][p], acc[1][p]};
    float2 o1 = {acc[2][p], acc[3][p]};
    float2 o2 = {acc[4][p], acc[5][p]};
    *(float2*)&o[0] = o0; *(float2*)&o[2] = o1; *(float2*)&o[4] = o2;
  }
}

// K1b: reduce 8 partials + bias + BN + ReLU + per-pixel LayerNorm -> xn (pixel-major)
__global__ void k_convred(const float* __restrict__ pbuf, const float* __restrict__ cb,
                          const float* __restrict__ bng, const float* __restrict__ bnb,
                          const float* __restrict__ bnm, const float* __restrict__ bnv,
                          const float* __restrict__ lng, const float* __restrict__ lnb,
                          float* __restrict__ xn){
  __shared__ float sm[4], sm2[4], smu[2], srs[2];
  int tid = threadIdx.x;
  int half = tid >> 7;           // 2 pixels per block
  int c = tid & 127;
  int pixg = blockIdx.x*2 + half;
  int b = pixg >> 12; int pix = pixg & (HW-1);
  float v = 0.f;
  if (c < CC){
    #pragma unroll
    for (int kc = 0; kc < 8; ++kc)
      v += pbuf[(((size_t)kc*2 + b)*HW + pix)*CC + c];
    v += cb[c];
    v = (v - bnm[c]) * rsqrtf(bnv[c] + 1e-5f);
    v = v * bng[c] + bnb[c];
    v = fmaxf(v, 0.f);
  }
  float s = v, s2 = v*v;
  #pragma unroll
  for (int off = 32; off; off >>= 1){ s += __shfl_down(s, off); s2 += __shfl_down(s2, off); }
  if ((tid & 63) == 0){ sm[tid>>6] = s; sm2[tid>>6] = s2; }
  __syncthreads();
  if (tid < 2){
    float ts = sm[2*tid] + sm[2*tid+1];
    float ts2 = sm2[2*tid] + sm2[2*tid+1];
    float mu = ts * (1.f/CC);
    float var = ts2 * (1.f/CC) - mu*mu;
    smu[tid] = mu; srs[tid] = rsqrtf(var + 1e-5f);
  }
  __syncthreads();
  if (c < CC)
    xn[(size_t)pixg*CC + c] = (v - smu[half])*srs[half]*lng[c] + lnb[c];
}

// K2b: xz(8192x384) = xn(8192x96) @ in_proj_w^T(96x384)
__global__ void k_inproj(const float* __restrict__ xn, const float* __restrict__ ipw,
                         float* __restrict__ xz){
  __shared__ float As[64][97];
  __shared__ __align__(16) float Bs[96][68];
  int p0 = blockIdx.x*64;
  int e0 = blockIdx.y*64;
  int tid = threadIdx.x;
  for (int idx = tid; idx < 64*96; idx += 256){
    int r = idx/96, c = idx - r*96;
    As[r][c] = xn[(size_t)(p0+r)*96 + c];
  }
  for (int idx = tid; idx < 96*64; idx += 256){
    int c = idx/64, e = idx - c*64;
    Bs[c][e] = ipw[(size_t)(e0+e)*96 + c];
  }
  __syncthreads();
  int tx = tid & 15, ty = tid >> 4;
  float acc[4][4] = {};
  for (int c = 0; c < 96; ++c){
    float a[4];
    #pragma unroll
    for (int i = 0; i < 4; ++i) a[i] = As[ty*4+i][c];
    float4 bb = *(const float4*)&Bs[c][tx*4];
    float bv[4] = {bb.x, bb.y, bb.z, bb.w};
    #pragma unroll
    for (int i = 0; i < 4; ++i)
      #pragma unroll
      for (int j = 0; j < 4; ++j) acc[i][j] += a[i]*bv[j];
  }
  for (int i = 0; i < 4; ++i){
    float4 o = {acc[i][0], acc[i][1], acc[i][2], acc[i][3]};
    *(float4*)&xz[(size_t)(p0+ty*4+i)*384 + e0 + tx*4] = o;
  }
}

// K3: depthwise 3x3 conv + bias + SiLU -> xc (B, L, 192)
__global__ void k_dwconv(const float* __restrict__ xz, const float* __restrict__ dww,
                         const float* __restrict__ dwb, float* __restrict__ xc){
  int tid = blockIdx.x*256 + threadIdx.x;   // ((b*HW+pix)*DD + d), d fast
  int d  = tid % DD;
  int bp = tid / DD;
  int pix = bp & (HW-1); int b = bp >> 12;
  int h = pix >> 6, w = pix & 63;
  float acc = dwb[d];
  #pragma unroll
  for (int dh = -1; dh <= 1; ++dh){
    int hh = h + dh;
    if (hh < 0 || hh > 63) continue;
    #pragma unroll
    for (int dw = -1; dw <= 1; ++dw){
      int ww = w + dw;
      if (ww < 0 || ww > 63) continue;
      acc += xz[((size_t)b*HW + hh*64 + ww)*384 + d] * dww[d*9 + (dh+1)*3 + (dw+1)];
    }
  }
  xc[(size_t)bp*DD + d] = siluf(acc);
}

// K4: x_dbl projections -> Bs(B,K,L,16), Cs(B,K,L,16), delta(B,K,L,192) (softplus applied)
__global__ void k_xdbl(const float* __restrict__ xc, const float* __restrict__ xpw,
                       const float* __restrict__ dtw, const float* __restrict__ dtb,
                       float* __restrict__ Bsb, float* __restrict__ Csb,
                       float* __restrict__ dlt){
  __shared__ float xs_t[8][194];
  __shared__ float wl[38*194];
  __shared__ float dts_t[8][38];
  int blk = blockIdx.x;
  int lc = blk & 511; int k = (blk >> 9) & 3; int b = blk >> 11;
  int l0 = lc*8;
  int tid = threadIdx.x;
  for (int idx = tid; idx < 38*192; idx += 256){
    int c = idx/192, d = idx - c*192;
    wl[c*194 + d] = xpw[(size_t)(k*38 + c)*192 + d];
  }
  for (int idx = tid; idx < 8*192; idx += 256){
    int li = idx/192, d = idx - li*192;
    int lm = lmap_xs(k, l0 + li);
    xs_t[li][d] = xc[((size_t)b*HW + lm)*DD + d];
  }
  __syncthreads();
  int b4k = b*KK + k;
  for (int o = tid; o < 8*38; o += 256){
    int li = o/38, c = o - li*38;
    const float* wrow = &wl[c*194];
    float s = 0.f;
    #pragma unroll 4
    for (int d = 0; d < 192; ++d) s += xs_t[li][d]*wrow[d];
    int l = l0 + li;
    if (c < 6)       dts_t[li][c] = s;
    else if (c < 22) Bsb[((size_t)b4k*HW + l)*NS + (c-6)]  = s;
    else             Csb[((size_t)b4k*HW + l)*NS + (c-22)] = s;
  }
  __syncthreads();
  for (int o = tid; o < 8*192; o += 256){
    int li = o/192, d = o - li*192;
    int l = l0 + li;
    float s = dtb[k*DD + d];
    #pragma unroll
    for (int r = 0; r < 6; ++r) s += dts_t[li][r]*dtw[(size_t)(k*DD+d)*6 + r];
    dlt[((size_t)b4k*HW + l)*DD + d] = softplusf(s);
  }
}

// K5a: per-chunk scan summaries. Thread owns (b4k, chunk, d), all 16 states in regs.
__global__ void k_scan1(const float* __restrict__ dlt, const float* __restrict__ xc,
                        const float* __restrict__ Bsb, const float* __restrict__ Alog,
                        float* __restrict__ Ac, float* __restrict__ Bc){
  int tid = blockIdx.x*256 + threadIdx.x;   // ((b4k*NC + chunk)*DD + d)
  int d = tid % DD;
  int rest = tid / DD;
  int chunk = rest & (NC-1);
  int b4k = rest >> 6;
  int k = b4k & 3, b = b4k >> 2;
  float Av[NS], h[NS], ap[NS];
  #pragma unroll
  for (int n = 0; n < NS; ++n){
    Av[n] = -expf(Alog[(size_t)(k*DD+d)*NS + n]);
    h[n] = 0.f; ap[n] = 1.f;
  }
  int l0 = chunk*LC;
  const float* dp  = dlt + ((size_t)b4k*HW + l0)*DD + d;
  const float* Bp  = Bsb + ((size_t)b4k*HW + l0)*NS;
  const float* xcb = xc  + (size_t)b*HW*DD + d;
  for (int i = 0; i < LC; ++i){
    float dv = dp[(size_t)i*DD];
    int lm = lmap_xs(k, l0 + i);
    float du = dv * xcb[(size_t)lm*DD];
    const float4* B4 = (const float4*)&Bp[i*NS];
    float4 b0 = B4[0], b1 = B4[1], b2 = B4[2], b3 = B4[3];
    float Bv[NS] = {b0.x,b0.y,b0.z,b0.w, b1.x,b1.y,b1.z,b1.w,
                    b2.x,b2.y,b2.z,b2.w, b3.x,b3.y,b3.z,b3.w};
    #pragma unroll
    for (int n = 0; n < NS; ++n){
      float a = __expf(dv*Av[n]);
      h[n] = h[n]*a + du*Bv[n];
      ap[n] *= a;
    }
  }
  size_t base = (size_t)chunk*NCH + (size_t)(b4k*DD + d)*NS;
  #pragma unroll
  for (int n = 0; n < NS; n += 4){
    *(float4*)&Ac[base+n] = make_float4(ap[n],ap[n+1],ap[n+2],ap[n+3]);
    *(float4*)&Bc[base+n] = make_float4(h[n],h[n+1],h[n+2],h[n+3]);
  }
}

// K5b: sequential prefix over chunk summaries; writes incoming state IN-PLACE over Ac.
__global__ void k_scan2(float* __restrict__ Ac, const float* __restrict__ Bc){
  int chain = blockIdx.x*256 + threadIdx.x;
  float h = 0.f;
  for (int c = 0; c < NC; ++c){
    size_t idx = (size_t)c*NCH + chain;
    float a = Ac[idx], bv = Bc[idx];
    Ac[idx] = h;
    h = a*h + bv;
  }
}

// K5c: re-run chunks with correct h0 (hst == Ac buffer), emit ys (B,K,L,192)
__global__ void k_scan3(const float* __restrict__ dlt, const float* __restrict__ xc,
                        const float* __restrict__ Bsb, const float* __restrict__ Csb,
                        const float* __restrict__ Alog, const float* __restrict__ hst,
                        float* __restrict__ ys){
  int tid = blockIdx.x*256 + threadIdx.x;
  int d = tid % DD;
  int rest = tid / DD;
  int chunk = rest & (NC-1);
  int b4k = rest >> 6;
  int k = b4k & 3, b = b4k >> 2;
  float Av[NS], h[NS];
  size_t hbase = (size_t)chunk*NCH + (size_t)(b4k*DD + d)*NS;
  #pragma unroll
  for (int n = 0; n < NS; ++n){
    Av[n] = -expf(Alog[(size_t)(k*DD+d)*NS + n]);
    h[n] = hst[hbase + n];
  }
  int l0 = chunk*LC;
  const float* dp  = dlt + ((size_t)b4k*HW + l0)*DD + d;
  const float* Bp  = Bsb + ((size_t)b4k*HW + l0)*NS;
  const float* Cp  = Csb + ((size_t)b4k*HW + l0)*NS;
  const float* xcb = xc  + (size_t)b*HW*DD + d;
  float* yp = ys + ((size_t)b4k*HW + l0)*DD + d;
  for (int i = 0; i < LC; ++i){
    float dv = dp[(size_t)i*DD];
    int lm = lmap_xs(k, l0 + i);
    float du = dv * xcb[(size_t)lm*DD];
    const float4* B4 = (const float4*)&Bp[i*NS];
    float4 b0 = B4[0], b1 = B4[1], b2 = B4[2], b3 = B4[3];
    float Bv[NS] = {b0.x,b0.y,b0.z,b0.w, b1.x,b1.y,b1.z,b1.w,
                    b2.x,b2.y,b2.z,b2.w, b3.x,b3.y,b3.z,b3.w};
    const float4* C4 = (const float4*)&Cp[i*NS];
    float4 c0 = C4[0], c1 = C4[1], c2 = C4[2], c3 = C4[3];
    float Cv[NS] = {c0.x,c0.y,c0.z,c0.w, c1.x,c1.y,c1.z,c1.w,
                    c2.x,c2.y,c2.z,c2.w, c3.x,c3.y,c3.z,c3.w};
    float y = 0.f;
    #pragma unroll
    for (int n = 0; n < NS; ++n){
      float a = __expf(dv*Av[n]);
      h[n] = h[n]*a + du*Bv[n];
      y += h[n]*Cv[n];
    }
    yp[(size_t)i*DD] = y;
  }
}

// K6: merge 4 directions + D*xs skip, LN over 192, *silu(z), out_proj 192->96, NCHW out
__global__ void k_merge(const float* __restrict__ ys, const float* __restrict__ xc,
                        const float* __restrict__ Ds, const float* __restrict__ xz,
                        const float* __restrict__ ong, const float* __restrict__ onb,
                        const float* __restrict__ opw, float* __restrict__ out){
  __shared__ float yd[DD];
  __shared__ float rs[4], rs2[4];
  __shared__ float smu, srstd;
  int blk = blockIdx.x; int b = blk >> 12; int l = blk & (HW-1);
  int tid = threadIdx.x;
  int l1 = ((l & 63) << 6) | (l >> 6);
  size_t base = (size_t)b*KK*HW*DD;
  float s = 0.f, s2 = 0.f;
  if (tid < DD){
    int d = tid;
    float v;
    v  = ys[base + ((size_t)0*HW + l         )*DD + d];
    v += ys[base + ((size_t)1*HW + l1        )*DD + d];
    v += ys[base + ((size_t)2*HW + (HW-1-l ) )*DD + d];
    v += ys[base + ((size_t)3*HW + (HW-1-l1) )*DD + d];
    float xcv = xc[((size_t)b*HW + l)*DD + d];
    float dsum = Ds[d] + Ds[DD+d] + Ds[2*DD+d] + Ds[3*DD+d];
    v += xcv * dsum;
    yd[d] = v;
    s = v; s2 = v*v;
  }
  #pragma unroll
  for (int off = 32; off; off >>= 1){ s += __shfl_down(s, off); s2 += __shfl_down(s2, off); }
  if ((tid & 63) == 0){ rs[tid>>6] = s; rs2[tid>>6] = s2; }
  __syncthreads();
  if (tid == 0){
    float ts  = rs[0]+rs[1]+rs[2]+rs[3];
    float ts2 = rs2[0]+rs2[1]+rs2[2]+rs2[3];
    float mu = ts*(1.f/DD);
    float var = ts2*(1.f/DD) - mu*mu;
    smu = mu; srstd = rsqrtf(var + 1e-5f);
  }
  __syncthreads();
  if (tid < DD){
    float x = (yd[tid]-smu)*srstd*ong[tid] + onb[tid];
    float z = xz[((size_t)b*HW + l)*384 + DD + tid];
    yd[tid] = x * siluf(z);
  }
  __syncthreads();
  if (tid < CC){
    float acc = 0.f;
    const float* wr = opw + (size_t)tid*DD;
    #pragma unroll 4
    for (int d = 0; d < DD; ++d) acc += yd[d]*wr[d];
    out[((size_t)b*CC + tid)*HW + l] = acc;
  }
}

extern "C" void kernel_launch(void* const* d_in, const int* in_sizes, int n_in,
                              void* d_out, int out_size, void* d_ws, size_t ws_size,
                              hipStream_t stream) {
  const float* rgb   = (const float*)d_in[0];
  const float* tt    = (const float*)d_in[1];
  const float* cw    = (const float*)d_in[2];
  const float* cb    = (const float*)d_in[3];
  const float* bng   = (const float*)d_in[4];
  const float* bnb   = (const float*)d_in[5];
  const float* bnm   = (const float*)d_in[6];
  const float* bnv   = (const float*)d_in[7];
  const float* lng   = (const float*)d_in[8];
  const float* lnb   = (const float*)d_in[9];
  const float* ipw   = (const float*)d_in[10];
  const float* dww   = (const float*)d_in[11];
  const float* dwb   = (const float*)d_in[12];
  const float* xpw   = (const float*)d_in[13];
  const float* dtw   = (const float*)d_in[14];
  const float* dtb   = (const float*)d_in[15];
  const float* Alog  = (const float*)d_in[16];
  const float* Ds    = (const float*)d_in[17];
  const float* ong   = (const float*)d_in[18];
  const float* onb   = (const float*)d_in[19];
  const float* opw   = (const float*)d_in[20];
  float* out = (float*)d_out;

  float* ws = (float*)d_ws;
  // persistent regions:
  float* xn   = ws + 786432;                 // 786432 (pixel-major, post-LN)
  float* xz   = ws + 1572864;                // 3145728
  float* xc   = ws + 4718592;                // 1572864
  float* Bsb  = ws + 6291456;                // 524288
  float* Csb  = ws + 6815744;                // 524288
  float* dlt  = ws + 7340032;                // 6291456
  float* ysb  = ws + 13631488;               // 6291456  (end 19922944 floats ~76MB)
  // transient overlays:
  float* pbuf = ws + 1572864;                // 6291456 (xz+xc+Bsb+Csb+dlt-front; dead before k_inproj)
  float* Ac   = ws;                          // 1572864 (conv/xn scratch region; xn dead after inproj)
  float* Bc   = ysb;                         // 1572864 (front of ysb; dead before k_scan3 writes ys)
  // k_scan2 writes hst in-place over Ac; k_scan3 reads it from there.

  k_conv1<<<256, 512, 0, stream>>>(rgb, tt, cw, pbuf);
  k_convred<<<4096, 256, 0, stream>>>(pbuf, cb, bng, bnb, bnm, bnv, lng, lnb, xn);
  dim3 g2(128, 6);
  k_inproj<<<g2, 256, 0, stream>>>(xn, ipw, xz);
  k_dwconv<<<6144, 256, 0, stream>>>(xz, dww, dwb, xc);
  k_xdbl<<<4096, 256, 0, stream>>>(xc, xpw, dtw, dtb, Bsb, Csb, dlt);
  k_scan1<<<384, 256, 0, stream>>>(dlt, xc, Bsb, Alog, Ac, Bc);
  k_scan2<<<96, 256, 0, stream>>>(Ac, Bc);
  k_scan3<<<384, 256, 0, stream>>>(dlt, xc, Bsb, Csb, Alog, Ac, ysb);
  k_merge<<<8192, 256, 0, stream>>>(ysb, xc, Ds, xz, ong, onb, opw, out);
}

// Round 4
// 333.890 us; speedup vs baseline: 7.8830x; 1.4756x over previous
//
#include <hip/hip_runtime.h>
#include <math.h>

#define HW 4096
#define CC 96
#define DD 192
#define NS 16
#define KK 4
#define LC 64
#define NC 64
#define NCH (8*DD*NS)   // 24576 chains

__device__ __forceinline__ float siluf(float x){ return x / (1.f + expf(-x)); }
__device__ __forceinline__ float softplusf(float x){ return (x > 20.f) ? x : log1pf(expf(x)); }

__device__ __forceinline__ int lmap_xs(int k, int l){
  if (k == 1) return ((l & 63) << 6) | (l >> 6);
  if (k == 2) return (HW - 1) - l;
  if (k == 3) { int r = (HW - 1) - l; return ((r & 63) << 6) | (r >> 6); }
  return l;
}

// K1: conv3x3(192->96) partials, K-split over ci.
__global__ void __launch_bounds__(512, 2)
k_conv1(const float* __restrict__ rgb, const float* __restrict__ tt,
        const float* __restrict__ cw, float* __restrict__ pbuf){
  __shared__ float in_lds[8][10][68];
  __shared__ float w_lds[8][9][48];
  int bi = blockIdx.x;
  int kc  = bi & 7;        int ci0 = kc*24;
  int r2  = bi >> 3;
  int cog = r2 & 1;        int co0 = cog*48;
  int r3  = r2 >> 1;
  int b   = r3 & 1;
  int pt  = r3 >> 1;       int h0 = pt*8;
  int tid = threadIdx.x;
  int pg = tid & 63;  int r = pg >> 3;  int w0 = (pg & 7)*8;
  int cg = tid >> 6;  int co_t = cg*6;

  float acc[6][8];
  #pragma unroll
  for (int c = 0; c < 6; ++c)
    #pragma unroll
    for (int p = 0; p < 8; ++p) acc[c][p] = 0.f;

  for (int s = 0; s < 3; ++s){
    if (s) __syncthreads();
    for (int i = tid; i < 80; i += 512){ in_lds[i/10][i%10][0] = 0.f; in_lds[i/10][i%10][65] = 0.f; }
    for (int i = tid; i < 5120; i += 512){
      int ci = i / 640; int rr = (i % 640) / 64; int w = i & 63;
      int grow = h0 - 1 + rr;
      int cig = ci0 + s*8 + ci;
      float v = 0.f;
      if (grow >= 0 && grow < 64){
        const float* src = (cig < CC) ? (rgb + (size_t)(b*CC+cig)*HW)
                                      : (tt  + (size_t)(b*CC+cig-CC)*HW);
        v = src[grow*64 + w];
      }
      in_lds[ci][rr][w+1] = v;
    }
    for (int i = tid; i < 3456; i += 512){
      int co = i % 48; int rest = i / 48; int ci = rest / 9; int tap = rest % 9;
      int cig = ci0 + s*8 + ci;
      w_lds[ci][tap][co] = cw[((size_t)(co0+co)*192 + cig)*9 + tap];
    }
    __syncthreads();
    #pragma unroll
    for (int ci = 0; ci < 8; ++ci){
      float rowv[3][10];
      #pragma unroll
      for (int rr = 0; rr < 3; ++rr){
        const float* rp = &in_lds[ci][r+rr][w0];
        float4 a = *(const float4*)rp;
        float4 bb = *(const float4*)(rp+4);
        float2 cc = *(const float2*)(rp+8);
        rowv[rr][0]=a.x; rowv[rr][1]=a.y; rowv[rr][2]=a.z; rowv[rr][3]=a.w;
        rowv[rr][4]=bb.x; rowv[rr][5]=bb.y; rowv[rr][6]=bb.z; rowv[rr][7]=bb.w;
        rowv[rr][8]=cc.x; rowv[rr][9]=cc.y;
      }
      #pragma unroll
      for (int tap = 0; tap < 9; ++tap){
        int rt = tap/3, ct = tap - rt*3;
        float2 wa = *(const float2*)&w_lds[ci][tap][co_t];
        float2 wb = *(const float2*)&w_lds[ci][tap][co_t+2];
        float2 wc = *(const float2*)&w_lds[ci][tap][co_t+4];
        float wv[6] = {wa.x, wa.y, wb.x, wb.y, wc.x, wc.y};
        #pragma unroll
        for (int p = 0; p < 8; ++p){
          float iv = rowv[rt][p + ct];
          #pragma unroll
          for (int c = 0; c < 6; ++c) acc[c][p] += wv[c]*iv;
        }
      }
    }
  }
  #pragma unroll
  for (int p = 0; p < 8; ++p){
    int pix = (h0 + r)*64 + w0 + p;
    float* o = pbuf + (((size_t)kc*2 + b)*HW + pix)*CC + co0 + co_t;
    float2 o0 = {acc[0][p], acc[1][p]};
    float2 o1 = {acc[2][p], acc[3][p]};
    float2 o2 = {acc[4][p], acc[5][p]};
    *(float2*)&o[0] = o0; *(float2*)&o[2] = o1; *(float2*)&o[4] = o2;
  }
}

// K1b: reduce 8 partials + bias + BN + ReLU + per-pixel LayerNorm -> xn (pixel-major)
__global__ void k_convred(const float* __restrict__ pbuf, const float* __restrict__ cb,
                          const float* __restrict__ bng, const float* __restrict__ bnb,
                          const float* __restrict__ bnm, const float* __restrict__ bnv,
                          const float* __restrict__ lng, const float* __restrict__ lnb,
                          float* __restrict__ xn){
  __shared__ float sm[4], sm2[4], smu[2], srs[2];
  int tid = threadIdx.x;
  int half = tid >> 7;
  int c = tid & 127;
  int pixg = blockIdx.x*2 + half;
  int b = pixg >> 12; int pix = pixg & (HW-1);
  float v = 0.f;
  if (c < CC){
    #pragma unroll
    for (int kc = 0; kc < 8; ++kc)
      v += pbuf[(((size_t)kc*2 + b)*HW + pix)*CC + c];
    v += cb[c];
    v = (v - bnm[c]) * rsqrtf(bnv[c] + 1e-5f);
    v = v * bng[c] + bnb[c];
    v = fmaxf(v, 0.f);
  }
  float s = v, s2 = v*v;
  #pragma unroll
  for (int off = 32; off; off >>= 1){ s += __shfl_down(s, off); s2 += __shfl_down(s2, off); }
  if ((tid & 63) == 0){ sm[tid>>6] = s; sm2[tid>>6] = s2; }
  __syncthreads();
  if (tid < 2){
    float ts = sm[2*tid] + sm[2*tid+1];
    float ts2 = sm2[2*tid] + sm2[2*tid+1];
    float mu = ts * (1.f/CC);
    float var = ts2 * (1.f/CC) - mu*mu;
    smu[tid] = mu; srs[tid] = rsqrtf(var + 1e-5f);
  }
  __syncthreads();
  if (c < CC)
    xn[(size_t)pixg*CC + c] = (v - smu[half])*srs[half]*lng[c] + lnb[c];
}

// K2b: xz(8192x384) = xn(8192x96) @ in_proj_w^T(96x384)
__global__ void k_inproj(const float* __restrict__ xn, const float* __restrict__ ipw,
                         float* __restrict__ xz){
  __shared__ float As[64][97];
  __shared__ __align__(16) float Bs[96][68];
  int p0 = blockIdx.x*64;
  int e0 = blockIdx.y*64;
  int tid = threadIdx.x;
  for (int idx = tid; idx < 64*96; idx += 256){
    int r = idx/96, c = idx - r*96;
    As[r][c] = xn[(size_t)(p0+r)*96 + c];
  }
  for (int idx = tid; idx < 96*64; idx += 256){
    int c = idx/64, e = idx - c*64;
    Bs[c][e] = ipw[(size_t)(e0+e)*96 + c];
  }
  __syncthreads();
  int tx = tid & 15, ty = tid >> 4;
  float acc[4][4] = {};
  for (int c = 0; c < 96; ++c){
    float a[4];
    #pragma unroll
    for (int i = 0; i < 4; ++i) a[i] = As[ty*4+i][c];
    float4 bb = *(const float4*)&Bs[c][tx*4];
    float bv[4] = {bb.x, bb.y, bb.z, bb.w};
    #pragma unroll
    for (int i = 0; i < 4; ++i)
      #pragma unroll
      for (int j = 0; j < 4; ++j) acc[i][j] += a[i]*bv[j];
  }
  for (int i = 0; i < 4; ++i){
    float4 o = {acc[i][0], acc[i][1], acc[i][2], acc[i][3]};
    *(float4*)&xz[(size_t)(p0+ty*4+i)*384 + e0 + tx*4] = o;
  }
}

// K3: depthwise 3x3 conv + bias + SiLU -> xc (B, L, 192)
__global__ void k_dwconv(const float* __restrict__ xz, const float* __restrict__ dww,
                         const float* __restrict__ dwb, float* __restrict__ xc){
  int tid = blockIdx.x*256 + threadIdx.x;
  int d  = tid % DD;
  int bp = tid / DD;
  int pix = bp & (HW-1); int b = bp >> 12;
  int h = pix >> 6, w = pix & 63;
  float acc = dwb[d];
  #pragma unroll
  for (int dh = -1; dh <= 1; ++dh){
    int hh = h + dh;
    if (hh < 0 || hh > 63) continue;
    #pragma unroll
    for (int dw = -1; dw <= 1; ++dw){
      int ww = w + dw;
      if (ww < 0 || ww > 63) continue;
      acc += xz[((size_t)b*HW + hh*64 + ww)*384 + d] * dww[d*9 + (dh+1)*3 + (dw+1)];
    }
  }
  xc[(size_t)bp*DD + d] = siluf(acc);
}

// K4: x_dbl projections -> Bs(B,K,L,16), Cs(B,K,L,16), delta(B,K,L,192) (softplus applied)
__global__ void k_xdbl(const float* __restrict__ xc, const float* __restrict__ xpw,
                       const float* __restrict__ dtw, const float* __restrict__ dtb,
                       float* __restrict__ Bsb, float* __restrict__ Csb,
                       float* __restrict__ dlt){
  __shared__ float xs_t[8][194];
  __shared__ float wl[38*194];
  __shared__ float dts_t[8][38];
  int blk = blockIdx.x;
  int lc = blk & 511; int k = (blk >> 9) & 3; int b = blk >> 11;
  int l0 = lc*8;
  int tid = threadIdx.x;
  for (int idx = tid; idx < 38*192; idx += 256){
    int c = idx/192, d = idx - c*192;
    wl[c*194 + d] = xpw[(size_t)(k*38 + c)*192 + d];
  }
  for (int idx = tid; idx < 8*192; idx += 256){
    int li = idx/192, d = idx - li*192;
    int lm = lmap_xs(k, l0 + li);
    xs_t[li][d] = xc[((size_t)b*HW + lm)*DD + d];
  }
  __syncthreads();
  int b4k = b*KK + k;
  for (int o = tid; o < 8*38; o += 256){
    int li = o/38, c = o - li*38;
    const float* wrow = &wl[c*194];
    float s = 0.f;
    #pragma unroll 4
    for (int d = 0; d < 192; ++d) s += xs_t[li][d]*wrow[d];
    int l = l0 + li;
    if (c < 6)       dts_t[li][c] = s;
    else if (c < 22) Bsb[((size_t)b4k*HW + l)*NS + (c-6)]  = s;
    else             Csb[((size_t)b4k*HW + l)*NS + (c-22)] = s;
  }
  __syncthreads();
  for (int o = tid; o < 8*192; o += 256){
    int li = o/192, d = o - li*192;
    int l = l0 + li;
    float s = dtb[k*DD + d];
    #pragma unroll
    for (int r = 0; r < 6; ++r) s += dts_t[li][r]*dtw[(size_t)(k*DD+d)*6 + r];
    dlt[((size_t)b4k*HW + l)*DD + d] = softplusf(s);
  }
}

// K5a: per-chunk scan summaries. n-split: thread owns (b4k, chunk, d, ng) = 4 states.
// tid = ((b4k*NC + chunk)*DD + d)*4 + ng. Prefetched loads.
__global__ void k_scan1(const float* __restrict__ dlt, const float* __restrict__ xc,
                        const float* __restrict__ Bsb, const float* __restrict__ Alog,
                        float* __restrict__ Ac, float* __restrict__ Bc){
  int tid = blockIdx.x*256 + threadIdx.x;
  int ng = tid & 3;
  int t2 = tid >> 2;
  int d = t2 % DD;
  int rest = t2 / DD;
  int chunk = rest & (NC-1);
  int b4k = rest >> 6;
  int k = b4k & 3, b = b4k >> 2;
  float4 Af = *(const float4*)&Alog[(size_t)(k*DD+d)*NS + ng*4];
  float Av[4] = {-expf(Af.x), -expf(Af.y), -expf(Af.z), -expf(Af.w)};
  float h[4] = {0.f,0.f,0.f,0.f};
  float ap[4] = {1.f,1.f,1.f,1.f};
  int l0 = chunk*LC;
  const float* dp  = dlt + ((size_t)b4k*HW + l0)*DD + d;
  const float4* Bp4 = (const float4*)(Bsb + ((size_t)b4k*HW + l0)*NS) + ng;
  const float* xcb = xc + (size_t)b*HW*DD + d;
  float dvc = dp[0];
  float xvc = xcb[(size_t)lmap_xs(k, l0)*DD];
  float4 Bvc = Bp4[0];
  #pragma unroll 4
  for (int i = 0; i < LC; ++i){
    float dvn = 0.f, xvn = 0.f; float4 Bvn = {0.f,0.f,0.f,0.f};
    if (i+1 < LC){
      dvn = dp[(size_t)(i+1)*DD];
      xvn = xcb[(size_t)lmap_xs(k, l0+i+1)*DD];
      Bvn = Bp4[(size_t)(i+1)*4];
    }
    float du = dvc*xvc;
    float a0 = __expf(dvc*Av[0]), a1 = __expf(dvc*Av[1]),
          a2 = __expf(dvc*Av[2]), a3 = __expf(dvc*Av[3]);
    h[0] = h[0]*a0 + du*Bvc.x; ap[0] *= a0;
    h[1] = h[1]*a1 + du*Bvc.y; ap[1] *= a1;
    h[2] = h[2]*a2 + du*Bvc.z; ap[2] *= a2;
    h[3] = h[3]*a3 + du*Bvc.w; ap[3] *= a3;
    dvc = dvn; xvc = xvn; Bvc = Bvn;
  }
  size_t base = (size_t)chunk*NCH + (size_t)(b4k*DD + d)*NS + ng*4;
  *(float4*)&Ac[base] = make_float4(ap[0],ap[1],ap[2],ap[3]);
  *(float4*)&Bc[base] = make_float4(h[0],h[1],h[2],h[3]);
}

// K5b: sequential prefix over chunk summaries; writes incoming state IN-PLACE over Ac.
__global__ void k_scan2(float* __restrict__ Ac, const float* __restrict__ Bc){
  int chain = blockIdx.x*256 + threadIdx.x;
  float h = 0.f;
  for (int c = 0; c < NC; ++c){
    size_t idx = (size_t)c*NCH + chain;
    float a = Ac[idx], bv = Bc[idx];
    Ac[idx] = h;
    h = a*h + bv;
  }
}

// K5c: re-run chunks with correct h0 (hst == Ac buffer), emit ys. n-split + prefetch.
__global__ void k_scan3(const float* __restrict__ dlt, const float* __restrict__ xc,
                        const float* __restrict__ Bsb, const float* __restrict__ Csb,
                        const float* __restrict__ Alog, const float* __restrict__ hst,
                        float* __restrict__ ys){
  int tid = blockIdx.x*256 + threadIdx.x;
  int ng = tid & 3;
  int t2 = tid >> 2;
  int d = t2 % DD;
  int rest = t2 / DD;
  int chunk = rest & (NC-1);
  int b4k = rest >> 6;
  int k = b4k & 3, b = b4k >> 2;
  float4 Af = *(const float4*)&Alog[(size_t)(k*DD+d)*NS + ng*4];
  float Av[4] = {-expf(Af.x), -expf(Af.y), -expf(Af.z), -expf(Af.w)};
  size_t hbase = (size_t)chunk*NCH + (size_t)(b4k*DD + d)*NS + ng*4;
  float4 hf = *(const float4*)&hst[hbase];
  float h[4] = {hf.x, hf.y, hf.z, hf.w};
  int l0 = chunk*LC;
  const float* dp  = dlt + ((size_t)b4k*HW + l0)*DD + d;
  const float4* Bp4 = (const float4*)(Bsb + ((size_t)b4k*HW + l0)*NS) + ng;
  const float4* Cp4 = (const float4*)(Csb + ((size_t)b4k*HW + l0)*NS) + ng;
  const float* xcb = xc + (size_t)b*HW*DD + d;
  float* yp = ys + ((size_t)b4k*HW + l0)*DD + d;
  float dvc = dp[0];
  float xvc = xcb[(size_t)lmap_xs(k, l0)*DD];
  float4 Bvc = Bp4[0];
  float4 Cvc = Cp4[0];
  #pragma unroll 4
  for (int i = 0; i < LC; ++i){
    float dvn = 0.f, xvn = 0.f; float4 Bvn = {0.f,0.f,0.f,0.f}, Cvn = {0.f,0.f,0.f,0.f};
    if (i+1 < LC){
      dvn = dp[(size_t)(i+1)*DD];
      xvn = xcb[(size_t)lmap_xs(k, l0+i+1)*DD];
      Bvn = Bp4[(size_t)(i+1)*4];
      Cvn = Cp4[(size_t)(i+1)*4];
    }
    float du = dvc*xvc;
    float a0 = __expf(dvc*Av[0]), a1 = __expf(dvc*Av[1]),
          a2 = __expf(dvc*Av[2]), a3 = __expf(dvc*Av[3]);
    h[0] = h[0]*a0 + du*Bvc.x;
    h[1] = h[1]*a1 + du*Bvc.y;
    h[2] = h[2]*a2 + du*Bvc.z;
    h[3] = h[3]*a3 + du*Bvc.w;
    float y = h[0]*Cvc.x + h[1]*Cvc.y + h[2]*Cvc.z + h[3]*Cvc.w;
    y += __shfl_xor(y, 1, 4);
    y += __shfl_xor(y, 2, 4);
    if (ng == 0) yp[(size_t)i*DD] = y;
    dvc = dvn; xvc = xvn; Bvc = Bvn; Cvc = Cvn;
  }
}

// K6: merge 4 directions + D*xs skip, LN over 192, *silu(z), out_proj 192->96, NCHW out
__global__ void k_merge(const float* __restrict__ ys, const float* __restrict__ xc,
                        const float* __restrict__ Ds, const float* __restrict__ xz,
                        const float* __restrict__ ong, const float* __restrict__ onb,
                        const float* __restrict__ opw, float* __restrict__ out){
  __shared__ float yd[DD];
  __shared__ float rs[4], rs2[4];
  __shared__ float smu, srstd;
  int blk = blockIdx.x; int b = blk >> 12; int l = blk & (HW-1);
  int tid = threadIdx.x;
  int l1 = ((l & 63) << 6) | (l >> 6);
  size_t base = (size_t)b*KK*HW*DD;
  float s = 0.f, s2 = 0.f;
  if (tid < DD){
    int d = tid;
    float v;
    v  = ys[base + ((size_t)0*HW + l         )*DD + d];
    v += ys[base + ((size_t)1*HW + l1        )*DD + d];
    v += ys[base + ((size_t)2*HW + (HW-1-l ) )*DD + d];
    v += ys[base + ((size_t)3*HW + (HW-1-l1) )*DD + d];
    float xcv = xc[((size_t)b*HW + l)*DD + d];
    float dsum = Ds[d] + Ds[DD+d] + Ds[2*DD+d] + Ds[3*DD+d];
    v += xcv * dsum;
    yd[d] = v;
    s = v; s2 = v*v;
  }
  #pragma unroll
  for (int off = 32; off; off >>= 1){ s += __shfl_down(s, off); s2 += __shfl_down(s2, off); }
  if ((tid & 63) == 0){ rs[tid>>6] = s; rs2[tid>>6] = s2; }
  __syncthreads();
  if (tid == 0){
    float ts  = rs[0]+rs[1]+rs[2]+rs[3];
    float ts2 = rs2[0]+rs2[1]+rs2[2]+rs2[3];
    float mu = ts*(1.f/DD);
    float var = ts2*(1.f/DD) - mu*mu;
    smu = mu; srstd = rsqrtf(var + 1e-5f);
  }
  __syncthreads();
  if (tid < DD){
    float x = (yd[tid]-smu)*srstd*ong[tid] + onb[tid];
    float z = xz[((size_t)b*HW + l)*384 + DD + tid];
    yd[tid] = x * siluf(z);
  }
  __syncthreads();
  if (tid < CC){
    float acc = 0.f;
    const float* wr = opw + (size_t)tid*DD;
    #pragma unroll 4
    for (int d = 0; d < DD; ++d) acc += yd[d]*wr[d];
    out[((size_t)b*CC + tid)*HW + l] = acc;
  }
}

extern "C" void kernel_launch(void* const* d_in, const int* in_sizes, int n_in,
                              void* d_out, int out_size, void* d_ws, size_t ws_size,
                              hipStream_t stream) {
  const float* rgb   = (const float*)d_in[0];
  const float* tt    = (const float*)d_in[1];
  const float* cw    = (const float*)d_in[2];
  const float* cb    = (const float*)d_in[3];
  const float* bng   = (const float*)d_in[4];
  const float* bnb   = (const float*)d_in[5];
  const float* bnm   = (const float*)d_in[6];
  const float* bnv   = (const float*)d_in[7];
  const float* lng   = (const float*)d_in[8];
  const float* lnb   = (const float*)d_in[9];
  const float* ipw   = (const float*)d_in[10];
  const float* dww   = (const float*)d_in[11];
  const float* dwb   = (const float*)d_in[12];
  const float* xpw   = (const float*)d_in[13];
  const float* dtw   = (const float*)d_in[14];
  const float* dtb   = (const float*)d_in[15];
  const float* Alog  = (const float*)d_in[16];
  const float* Ds    = (const float*)d_in[17];
  const float* ong   = (const float*)d_in[18];
  const float* onb   = (const float*)d_in[19];
  const float* opw   = (const float*)d_in[20];
  float* out = (float*)d_out;

  float* ws = (float*)d_ws;
  // persistent regions:
  float* xn   = ws + 786432;                 // 786432 (pixel-major, post-LN)
  float* xz   = ws + 1572864;                // 3145728
  float* xc   = ws + 4718592;                // 1572864
  float* Bsb  = ws + 6291456;                // 524288
  float* Csb  = ws + 6815744;                // 524288
  float* dlt  = ws + 7340032;                // 6291456
  float* ysb  = ws + 13631488;               // 6291456  (end 19922944 floats ~76MB)
  // transient overlays:
  float* pbuf = ws + 1572864;                // 6291456 (xz..dlt-front; dead before k_inproj)
  float* Ac   = ws;                          // 1572864 (conv/xn region; xn dead after inproj)
  float* Bc   = ysb;                         // 1572864 (front of ysb; dead before k_scan3 writes ys)
  // k_scan2 writes hst in-place over Ac; k_scan3 reads it from there.

  k_conv1<<<256, 512, 0, stream>>>(rgb, tt, cw, pbuf);
  k_convred<<<4096, 256, 0, stream>>>(pbuf, cb, bng, bnb, bnm, bnv, lng, lnb, xn);
  dim3 g2(128, 6);
  k_inproj<<<g2, 256, 0, stream>>>(xn, ipw, xz);
  k_dwconv<<<6144, 256, 0, stream>>>(xz, dww, dwb, xc);
  k_xdbl<<<4096, 256, 0, stream>>>(xc, xpw, dtw, dtb, Bsb, Csb, dlt);
  k_scan1<<<1536, 256, 0, stream>>>(dlt, xc, Bsb, Alog, Ac, Bc);
  k_scan2<<<96, 256, 0, stream>>>(Ac, Bc);
  k_scan3<<<1536, 256, 0, stream>>>(dlt, xc, Bsb, Csb, Alog, Ac, ysb);
  k_merge<<<8192, 256, 0, stream>>>(ysb, xc, Ds, xz, ong, onb, opw, out);
}

// Round 5
// 277.765 us; speedup vs baseline: 9.4759x; 1.2021x over previous
//
#include <hip/hip_runtime.h>
#include <math.h>

#define HW 4096
#define CC 96
#define DD 192
#define NS 16
#define KK 4
#define LC 64
#define NC 64
#define NCH (8*DD*NS)   // 24576 chains

__device__ __forceinline__ float siluf(float x){ return x / (1.f + expf(-x)); }
__device__ __forceinline__ float softplusf(float x){ return (x > 20.f) ? x : log1pf(expf(x)); }

__device__ __forceinline__ int lmap_xs(int k, int l){
  if (k == 1) return ((l & 63) << 6) | (l >> 6);
  if (k == 2) return (HW - 1) - l;
  if (k == 3) { int r = (HW - 1) - l; return ((r & 63) << 6) | (r >> 6); }
  return l;
}

// K1: conv3x3(192->96) partials, K-split over ci.
__global__ void __launch_bounds__(512, 2)
k_conv1(const float* __restrict__ rgb, const float* __restrict__ tt,
        const float* __restrict__ cw, float* __restrict__ pbuf){
  __shared__ float in_lds[8][10][68];
  __shared__ float w_lds[8][9][48];
  int bi = blockIdx.x;
  int kc  = bi & 7;        int ci0 = kc*24;
  int r2  = bi >> 3;
  int cog = r2 & 1;        int co0 = cog*48;
  int r3  = r2 >> 1;
  int b   = r3 & 1;
  int pt  = r3 >> 1;       int h0 = pt*8;
  int tid = threadIdx.x;
  int pg = tid & 63;  int r = pg >> 3;  int w0 = (pg & 7)*8;
  int cg = tid >> 6;  int co_t = cg*6;

  float acc[6][8];
  #pragma unroll
  for (int c = 0; c < 6; ++c)
    #pragma unroll
    for (int p = 0; p < 8; ++p) acc[c][p] = 0.f;

  for (int s = 0; s < 3; ++s){
    if (s) __syncthreads();
    for (int i = tid; i < 80; i += 512){ in_lds[i/10][i%10][0] = 0.f; in_lds[i/10][i%10][65] = 0.f; }
    for (int i = tid; i < 5120; i += 512){
      int ci = i / 640; int rr = (i % 640) / 64; int w = i & 63;
      int grow = h0 - 1 + rr;
      int cig = ci0 + s*8 + ci;
      float v = 0.f;
      if (grow >= 0 && grow < 64){
        const float* src = (cig < CC) ? (rgb + (size_t)(b*CC+cig)*HW)
                                      : (tt  + (size_t)(b*CC+cig-CC)*HW);
        v = src[grow*64 + w];
      }
      in_lds[ci][rr][w+1] = v;
    }
    for (int i = tid; i < 3456; i += 512){
      int co = i % 48; int rest = i / 48; int ci = rest / 9; int tap = rest % 9;
      int cig = ci0 + s*8 + ci;
      w_lds[ci][tap][co] = cw[((size_t)(co0+co)*192 + cig)*9 + tap];
    }
    __syncthreads();
    #pragma unroll
    for (int ci = 0; ci < 8; ++ci){
      float rowv[3][10];
      #pragma unroll
      for (int rr = 0; rr < 3; ++rr){
        const float* rp = &in_lds[ci][r+rr][w0];
        float4 a = *(const float4*)rp;
        float4 bb = *(const float4*)(rp+4);
        float2 cc = *(const float2*)(rp+8);
        rowv[rr][0]=a.x; rowv[rr][1]=a.y; rowv[rr][2]=a.z; rowv[rr][3]=a.w;
        rowv[rr][4]=bb.x; rowv[rr][5]=bb.y; rowv[rr][6]=bb.z; rowv[rr][7]=bb.w;
        rowv[rr][8]=cc.x; rowv[rr][9]=cc.y;
      }
      #pragma unroll
      for (int tap = 0; tap < 9; ++tap){
        int rt = tap/3, ct = tap - rt*3;
        float2 wa = *(const float2*)&w_lds[ci][tap][co_t];
        float2 wb = *(const float2*)&w_lds[ci][tap][co_t+2];
        float2 wc = *(const float2*)&w_lds[ci][tap][co_t+4];
        float wv[6] = {wa.x, wa.y, wb.x, wb.y, wc.x, wc.y};
        #pragma unroll
        for (int p = 0; p < 8; ++p){
          float iv = rowv[rt][p + ct];
          #pragma unroll
          for (int c = 0; c < 6; ++c) acc[c][p] += wv[c]*iv;
        }
      }
    }
  }
  #pragma unroll
  for (int p = 0; p < 8; ++p){
    int pix = (h0 + r)*64 + w0 + p;
    float* o = pbuf + (((size_t)kc*2 + b)*HW + pix)*CC + co0 + co_t;
    float2 o0 = {acc[0][p], acc[1][p]};
    float2 o1 = {acc[2][p], acc[3][p]};
    float2 o2 = {acc[4][p], acc[5][p]};
    *(float2*)&o[0] = o0; *(float2*)&o[2] = o1; *(float2*)&o[4] = o2;
  }
}

// K1b: reduce 8 partials + bias + BN + ReLU + per-pixel LayerNorm -> xn (pixel-major)
__global__ void k_convred(const float* __restrict__ pbuf, const float* __restrict__ cb,
                          const float* __restrict__ bng, const float* __restrict__ bnb,
                          const float* __restrict__ bnm, const float* __restrict__ bnv,
                          const float* __restrict__ lng, const float* __restrict__ lnb,
                          float* __restrict__ xn){
  __shared__ float sm[4], sm2[4], smu[2], srs[2];
  int tid = threadIdx.x;
  int half = tid >> 7;
  int c = tid & 127;
  int pixg = blockIdx.x*2 + half;
  int b = pixg >> 12; int pix = pixg & (HW-1);
  float v = 0.f;
  if (c < CC){
    #pragma unroll
    for (int kc = 0; kc < 8; ++kc)
      v += pbuf[(((size_t)kc*2 + b)*HW + pix)*CC + c];
    v += cb[c];
    v = (v - bnm[c]) * rsqrtf(bnv[c] + 1e-5f);
    v = v * bng[c] + bnb[c];
    v = fmaxf(v, 0.f);
  }
  float s = v, s2 = v*v;
  #pragma unroll
  for (int off = 32; off; off >>= 1){ s += __shfl_down(s, off); s2 += __shfl_down(s2, off); }
  if ((tid & 63) == 0){ sm[tid>>6] = s; sm2[tid>>6] = s2; }
  __syncthreads();
  if (tid < 2){
    float ts = sm[2*tid] + sm[2*tid+1];
    float ts2 = sm2[2*tid] + sm2[2*tid+1];
    float mu = ts * (1.f/CC);
    float var = ts2 * (1.f/CC) - mu*mu;
    smu[tid] = mu; srs[tid] = rsqrtf(var + 1e-5f);
  }
  __syncthreads();
  if (c < CC)
    xn[(size_t)pixg*CC + c] = (v - smu[half])*srs[half]*lng[c] + lnb[c];
}

// K2b: xz(8192x384) = xn(8192x96) @ in_proj_w^T(96x384)
__global__ void k_inproj(const float* __restrict__ xn, const float* __restrict__ ipw,
                         float* __restrict__ xz){
  __shared__ float As[64][97];
  __shared__ __align__(16) float Bs[96][68];
  int p0 = blockIdx.x*64;
  int e0 = blockIdx.y*64;
  int tid = threadIdx.x;
  for (int idx = tid; idx < 64*96; idx += 256){
    int r = idx/96, c = idx - r*96;
    As[r][c] = xn[(size_t)(p0+r)*96 + c];
  }
  for (int idx = tid; idx < 96*64; idx += 256){
    int c = idx/64, e = idx - c*64;
    Bs[c][e] = ipw[(size_t)(e0+e)*96 + c];
  }
  __syncthreads();
  int tx = tid & 15, ty = tid >> 4;
  float acc[4][4] = {};
  for (int c = 0; c < 96; ++c){
    float a[4];
    #pragma unroll
    for (int i = 0; i < 4; ++i) a[i] = As[ty*4+i][c];
    float4 bb = *(const float4*)&Bs[c][tx*4];
    float bv[4] = {bb.x, bb.y, bb.z, bb.w};
    #pragma unroll
    for (int i = 0; i < 4; ++i)
      #pragma unroll
      for (int j = 0; j < 4; ++j) acc[i][j] += a[i]*bv[j];
  }
  for (int i = 0; i < 4; ++i){
    float4 o = {acc[i][0], acc[i][1], acc[i][2], acc[i][3]};
    *(float4*)&xz[(size_t)(p0+ty*4+i)*384 + e0 + tx*4] = o;
  }
}

// K3: depthwise 3x3 conv + bias + SiLU -> xc (B, L, 192)
__global__ void k_dwconv(const float* __restrict__ xz, const float* __restrict__ dww,
                         const float* __restrict__ dwb, float* __restrict__ xc){
  int tid = blockIdx.x*256 + threadIdx.x;
  int d  = tid % DD;
  int bp = tid / DD;
  int pix = bp & (HW-1); int b = bp >> 12;
  int h = pix >> 6, w = pix & 63;
  float acc = dwb[d];
  #pragma unroll
  for (int dh = -1; dh <= 1; ++dh){
    int hh = h + dh;
    if (hh < 0 || hh > 63) continue;
    #pragma unroll
    for (int dw = -1; dw <= 1; ++dw){
      int ww = w + dw;
      if (ww < 0 || ww > 63) continue;
      acc += xz[((size_t)b*HW + hh*64 + ww)*384 + d] * dww[d*9 + (dh+1)*3 + (dw+1)];
    }
  }
  xc[(size_t)bp*DD + d] = siluf(acc);
}

// K4: x_dbl projections -> Bs(B,K,L,16), Cs(B,K,L,16), delta(B,K,L,192) (softplus applied)
__global__ void k_xdbl(const float* __restrict__ xc, const float* __restrict__ xpw,
                       const float* __restrict__ dtw, const float* __restrict__ dtb,
                       float* __restrict__ Bsb, float* __restrict__ Csb,
                       float* __restrict__ dlt){
  __shared__ float xs_t[8][194];
  __shared__ float wl[38*194];
  __shared__ float dts_t[8][38];
  int blk = blockIdx.x;
  int lc = blk & 511; int k = (blk >> 9) & 3; int b = blk >> 11;
  int l0 = lc*8;
  int tid = threadIdx.x;
  for (int idx = tid; idx < 38*192; idx += 256){
    int c = idx/192, d = idx - c*192;
    wl[c*194 + d] = xpw[(size_t)(k*38 + c)*192 + d];
  }
  for (int idx = tid; idx < 8*192; idx += 256){
    int li = idx/192, d = idx - li*192;
    int lm = lmap_xs(k, l0 + li);
    xs_t[li][d] = xc[((size_t)b*HW + lm)*DD + d];
  }
  __syncthreads();
  int b4k = b*KK + k;
  for (int o = tid; o < 8*38; o += 256){
    int li = o/38, c = o - li*38;
    const float* wrow = &wl[c*194];
    float s = 0.f;
    #pragma unroll 4
    for (int d = 0; d < 192; ++d) s += xs_t[li][d]*wrow[d];
    int l = l0 + li;
    if (c < 6)       dts_t[li][c] = s;
    else if (c < 22) Bsb[((size_t)b4k*HW + l)*NS + (c-6)]  = s;
    else             Csb[((size_t)b4k*HW + l)*NS + (c-22)] = s;
  }
  __syncthreads();
  for (int o = tid; o < 8*192; o += 256){
    int li = o/192, d = o - li*192;
    int l = l0 + li;
    float s = dtb[k*DD + d];
    #pragma unroll
    for (int r = 0; r < 6; ++r) s += dts_t[li][r]*dtw[(size_t)(k*DD+d)*6 + r];
    dlt[((size_t)b4k*HW + l)*DD + d] = softplusf(s);
  }
}

// K5a: per-chunk scan summaries. n-split: thread owns (b4k, chunk, d, ng) = 4 states.
__global__ void k_scan1(const float* __restrict__ dlt, const float* __restrict__ xc,
                        const float* __restrict__ Bsb, const float* __restrict__ Alog,
                        float* __restrict__ Ac, float* __restrict__ Bc){
  int tid = blockIdx.x*256 + threadIdx.x;
  int ng = tid & 3;
  int t2 = tid >> 2;
  int d = t2 % DD;
  int rest = t2 / DD;
  int chunk = rest & (NC-1);
  int b4k = rest >> 6;
  int k = b4k & 3, b = b4k >> 2;
  float4 Af = *(const float4*)&Alog[(size_t)(k*DD+d)*NS + ng*4];
  float Av[4] = {-expf(Af.x), -expf(Af.y), -expf(Af.z), -expf(Af.w)};
  float h[4] = {0.f,0.f,0.f,0.f};
  float ap[4] = {1.f,1.f,1.f,1.f};
  int l0 = chunk*LC;
  const float* dp  = dlt + ((size_t)b4k*HW + l0)*DD + d;
  const float4* Bp4 = (const float4*)(Bsb + ((size_t)b4k*HW + l0)*NS) + ng;
  const float* xcb = xc + (size_t)b*HW*DD + d;
  float dvc = dp[0];
  float xvc = xcb[(size_t)lmap_xs(k, l0)*DD];
  float4 Bvc = Bp4[0];
  #pragma unroll 4
  for (int i = 0; i < LC; ++i){
    float dvn = 0.f, xvn = 0.f; float4 Bvn = {0.f,0.f,0.f,0.f};
    if (i+1 < LC){
      dvn = dp[(size_t)(i+1)*DD];
      xvn = xcb[(size_t)lmap_xs(k, l0+i+1)*DD];
      Bvn = Bp4[(size_t)(i+1)*4];
    }
    float du = dvc*xvc;
    float a0 = __expf(dvc*Av[0]), a1 = __expf(dvc*Av[1]),
          a2 = __expf(dvc*Av[2]), a3 = __expf(dvc*Av[3]);
    h[0] = h[0]*a0 + du*Bvc.x; ap[0] *= a0;
    h[1] = h[1]*a1 + du*Bvc.y; ap[1] *= a1;
    h[2] = h[2]*a2 + du*Bvc.z; ap[2] *= a2;
    h[3] = h[3]*a3 + du*Bvc.w; ap[3] *= a3;
    dvc = dvn; xvc = xvn; Bvc = Bvn;
  }
  size_t base = (size_t)chunk*NCH + (size_t)(b4k*DD + d)*NS + ng*4;
  *(float4*)&Ac[base] = make_float4(ap[0],ap[1],ap[2],ap[3]);
  *(float4*)&Bc[base] = make_float4(h[0],h[1],h[2],h[3]);
}

// K5b: sequential prefix over chunk summaries; writes incoming state IN-PLACE over Ac.
__global__ void k_scan2(float* __restrict__ Ac, const float* __restrict__ Bc){
  int chain = blockIdx.x*256 + threadIdx.x;
  float h = 0.f;
  for (int c = 0; c < NC; ++c){
    size_t idx = (size_t)c*NCH + chain;
    float a = Ac[idx], bv = Bc[idx];
    Ac[idx] = h;
    h = a*h + bv;
  }
}

// K5c: re-run chunks with correct h0 (hst == Ac buffer), emit ys. n-split + prefetch.
__global__ void k_scan3(const float* __restrict__ dlt, const float* __restrict__ xc,
                        const float* __restrict__ Bsb, const float* __restrict__ Csb,
                        const float* __restrict__ Alog, const float* __restrict__ hst,
                        float* __restrict__ ys){
  int tid = blockIdx.x*256 + threadIdx.x;
  int ng = tid & 3;
  int t2 = tid >> 2;
  int d = t2 % DD;
  int rest = t2 / DD;
  int chunk = rest & (NC-1);
  int b4k = rest >> 6;
  int k = b4k & 3, b = b4k >> 2;
  float4 Af = *(const float4*)&Alog[(size_t)(k*DD+d)*NS + ng*4];
  float Av[4] = {-expf(Af.x), -expf(Af.y), -expf(Af.z), -expf(Af.w)};
  size_t hbase = (size_t)chunk*NCH + (size_t)(b4k*DD + d)*NS + ng*4;
  float4 hf = *(const float4*)&hst[hbase];
  float h[4] = {hf.x, hf.y, hf.z, hf.w};
  int l0 = chunk*LC;
  const float* dp  = dlt + ((size_t)b4k*HW + l0)*DD + d;
  const float4* Bp4 = (const float4*)(Bsb + ((size_t)b4k*HW + l0)*NS) + ng;
  const float4* Cp4 = (const float4*)(Csb + ((size_t)b4k*HW + l0)*NS) + ng;
  const float* xcb = xc + (size_t)b*HW*DD + d;
  float* yp = ys + ((size_t)b4k*HW + l0)*DD + d;
  float dvc = dp[0];
  float xvc = xcb[(size_t)lmap_xs(k, l0)*DD];
  float4 Bvc = Bp4[0];
  float4 Cvc = Cp4[0];
  #pragma unroll 4
  for (int i = 0; i < LC; ++i){
    float dvn = 0.f, xvn = 0.f; float4 Bvn = {0.f,0.f,0.f,0.f}, Cvn = {0.f,0.f,0.f,0.f};
    if (i+1 < LC){
      dvn = dp[(size_t)(i+1)*DD];
      xvn = xcb[(size_t)lmap_xs(k, l0+i+1)*DD];
      Bvn = Bp4[(size_t)(i+1)*4];
      Cvn = Cp4[(size_t)(i+1)*4];
    }
    float du = dvc*xvc;
    float a0 = __expf(dvc*Av[0]), a1 = __expf(dvc*Av[1]),
          a2 = __expf(dvc*Av[2]), a3 = __expf(dvc*Av[3]);
    h[0] = h[0]*a0 + du*Bvc.x;
    h[1] = h[1]*a1 + du*Bvc.y;
    h[2] = h[2]*a2 + du*Bvc.z;
    h[3] = h[3]*a3 + du*Bvc.w;
    float y = h[0]*Cvc.x + h[1]*Cvc.y + h[2]*Cvc.z + h[3]*Cvc.w;
    y += __shfl_xor(y, 1, 4);
    y += __shfl_xor(y, 2, 4);
    if (ng == 0) yp[(size_t)i*DD] = y;
    dvc = dvn; xvc = xvn; Bvc = Bvn; Cvc = Cvn;
  }
}

// K6a: merge 4 dirs + D*xs skip, LN over 192, *silu(z) -> yg (B,L,192). Wave per pixel.
__global__ void k_gate(const float* __restrict__ ys, const float* __restrict__ xc,
                       const float* __restrict__ Ds, const float* __restrict__ xz,
                       const float* __restrict__ ong, const float* __restrict__ onb,
                       float* __restrict__ yg){
  int gt = blockIdx.x*256 + threadIdx.x;
  int wave = gt >> 6;                // global pixel index (b*HW + l)
  int lane = gt & 63;
  int b = wave >> 12; int l = wave & (HW-1);
  int l1 = ((l & 63) << 6) | (l >> 6);
  size_t base = (size_t)b*KK*HW*DD;
  float v[3]; float s = 0.f, s2 = 0.f;
  #pragma unroll
  for (int j = 0; j < 3; ++j){
    int d = lane + j*64;
    float t;
    t  = ys[base + ((size_t)0*HW + l        )*DD + d];
    t += ys[base + ((size_t)1*HW + l1       )*DD + d];
    t += ys[base + ((size_t)2*HW + (HW-1-l ))*DD + d];
    t += ys[base + ((size_t)3*HW + (HW-1-l1))*DD + d];
    t += xc[((size_t)b*HW + l)*DD + d] * (Ds[d] + Ds[DD+d] + Ds[2*DD+d] + Ds[3*DD+d]);
    v[j] = t; s += t; s2 += t*t;
  }
  #pragma unroll
  for (int off = 32; off; off >>= 1){ s += __shfl_xor(s, off); s2 += __shfl_xor(s2, off); }
  float mu = s*(1.f/DD);
  float rstd = rsqrtf(s2*(1.f/DD) - mu*mu + 1e-5f);
  #pragma unroll
  for (int j = 0; j < 3; ++j){
    int d = lane + j*64;
    float z = xz[((size_t)b*HW + l)*384 + DD + d];
    float x = (v[j]-mu)*rstd*ong[d] + onb[d];
    yg[(size_t)wave*DD + d] = x * siluf(z);
  }
}

// K6b: out = yg(8192x192) @ opw^T(192x96), NCHW write. 32px x 96c per block.
__global__ void k_outproj(const float* __restrict__ yg, const float* __restrict__ opw,
                          float* __restrict__ out){
  __shared__ float yl[48][36];   // [k][px], pad
  __shared__ float wl[48][97];   // [k][c], pad
  int blk = blockIdx.x;          // b*128 + pt
  int b = blk >> 7; int pt = blk & 127;
  int px0 = pt*32;
  int tid = threadIdx.x;
  int pxg = tid & 7;             // 8 groups x 4 px
  int cgi = tid >> 3;            // 32 groups x 3 c
  float acc[4][3] = {};
  for (int k0 = 0; k0 < DD; k0 += 48){
    if (k0) __syncthreads();
    for (int i = tid; i < 32*48; i += 256){
      int r = i/48, k = i - r*48;
      yl[k][r] = yg[((size_t)b*HW + px0 + r)*DD + k0 + k];
    }
    for (int i = tid; i < 96*48; i += 256){
      int c = i/48, k = i - c*48;
      wl[k][c] = opw[(size_t)c*DD + k0 + k];
    }
    __syncthreads();
    #pragma unroll 4
    for (int k = 0; k < 48; ++k){
      float4 yv = *(const float4*)&yl[k][pxg*4];
      float w0 = wl[k][cgi*3], w1 = wl[k][cgi*3+1], w2 = wl[k][cgi*3+2];
      acc[0][0] += yv.x*w0; acc[0][1] += yv.x*w1; acc[0][2] += yv.x*w2;
      acc[1][0] += yv.y*w0; acc[1][1] += yv.y*w1; acc[1][2] += yv.y*w2;
      acc[2][0] += yv.z*w0; acc[2][1] += yv.z*w1; acc[2][2] += yv.z*w2;
      acc[3][0] += yv.w*w0; acc[3][1] += yv.w*w1; acc[3][2] += yv.w*w2;
    }
  }
  #pragma unroll
  for (int j = 0; j < 3; ++j){
    int c = cgi*3 + j;
    float4 o = {acc[0][j], acc[1][j], acc[2][j], acc[3][j]};
    *(float4*)&out[((size_t)b*CC + c)*HW + px0 + pxg*4] = o;
  }
}

extern "C" void kernel_launch(void* const* d_in, const int* in_sizes, int n_in,
                              void* d_out, int out_size, void* d_ws, size_t ws_size,
                              hipStream_t stream) {
  const float* rgb   = (const float*)d_in[0];
  const float* tt    = (const float*)d_in[1];
  const float* cw    = (const float*)d_in[2];
  const float* cb    = (const float*)d_in[3];
  const float* bng   = (const float*)d_in[4];
  const float* bnb   = (const float*)d_in[5];
  const float* bnm   = (const float*)d_in[6];
  const float* bnv   = (const float*)d_in[7];
  const float* lng   = (const float*)d_in[8];
  const float* lnb   = (const float*)d_in[9];
  const float* ipw   = (const float*)d_in[10];
  const float* dww   = (const float*)d_in[11];
  const float* dwb   = (const float*)d_in[12];
  const float* xpw   = (const float*)d_in[13];
  const float* dtw   = (const float*)d_in[14];
  const float* dtb   = (const float*)d_in[15];
  const float* Alog  = (const float*)d_in[16];
  const float* Ds    = (const float*)d_in[17];
  const float* ong   = (const float*)d_in[18];
  const float* onb   = (const float*)d_in[19];
  const float* opw   = (const float*)d_in[20];
  float* out = (float*)d_out;

  float* ws = (float*)d_ws;
  // persistent regions:
  float* xn   = ws + 786432;                 // 786432 (pixel-major, post-LN)
  float* xz   = ws + 1572864;                // 3145728
  float* xc   = ws + 4718592;                // 1572864
  float* Bsb  = ws + 6291456;                // 524288
  float* Csb  = ws + 6815744;                // 524288
  float* dlt  = ws + 7340032;                // 6291456
  float* ysb  = ws + 13631488;               // 6291456  (end 19922944 floats ~76MB)
  // transient overlays:
  float* pbuf = ws + 1572864;                // 6291456 (xz..dlt-front; dead before k_inproj)
  float* Ac   = ws;                          // 1572864 (conv/xn region; xn dead after inproj)
  float* Bc   = ysb;                         // 1572864 (front of ysb; dead before k_scan3 writes ys)
  float* yg   = ws + 7340032;                // 1572864 (over dlt; dlt dead after k_scan3)
  // k_scan2 writes hst in-place over Ac; k_scan3 reads it from there.

  k_conv1<<<256, 512, 0, stream>>>(rgb, tt, cw, pbuf);
  k_convred<<<4096, 256, 0, stream>>>(pbuf, cb, bng, bnb, bnm, bnv, lng, lnb, xn);
  dim3 g2(128, 6);
  k_inproj<<<g2, 256, 0, stream>>>(xn, ipw, xz);
  k_dwconv<<<6144, 256, 0, stream>>>(xz, dww, dwb, xc);
  k_xdbl<<<4096, 256, 0, stream>>>(xc, xpw, dtw, dtb, Bsb, Csb, dlt);
  k_scan1<<<1536, 256, 0, stream>>>(dlt, xc, Bsb, Alog, Ac, Bc);
  k_scan2<<<96, 256, 0, stream>>>(Ac, Bc);
  k_scan3<<<1536, 256, 0, stream>>>(dlt, xc, Bsb, Csb, Alog, Ac, ysb);
  k_gate<<<2048, 256, 0, stream>>>(ysb, xc, Ds, xz, ong, onb, yg);
  k_outproj<<<256, 256, 0, stream>>>(yg, opw, out);
}

// Round 6
// 258.495 us; speedup vs baseline: 10.1823x; 1.0745x over previous
//
#include <hip/hip_runtime.h>
#include <math.h>

#define HW 4096
#define CC 96
#define DD 192
#define NS 16
#define KK 4
#define LC 64
#define NC 64
#define NCH (8*DD*NS)   // 24576 chains

__device__ __forceinline__ float siluf(float x){ return x / (1.f + expf(-x)); }
__device__ __forceinline__ float softplusf(float x){ return (x > 20.f) ? x : log1pf(expf(x)); }

__device__ __forceinline__ int lmap_xs(int k, int l){
  if (k == 1) return ((l & 63) << 6) | (l >> 6);
  if (k == 2) return (HW - 1) - l;
  if (k == 3) { int r = (HW - 1) - l; return ((r & 63) << 6) | (r >> 6); }
  return l;
}

// K1: conv3x3(192->96) partials, K-split over ci.
__global__ void __launch_bounds__(512, 2)
k_conv1(const float* __restrict__ rgb, const float* __restrict__ tt,
        const float* __restrict__ cw, float* __restrict__ pbuf){
  __shared__ float in_lds[8][10][68];
  __shared__ float w_lds[8][9][48];
  int bi = blockIdx.x;
  int kc  = bi & 7;        int ci0 = kc*24;
  int r2  = bi >> 3;
  int cog = r2 & 1;        int co0 = cog*48;
  int r3  = r2 >> 1;
  int b   = r3 & 1;
  int pt  = r3 >> 1;       int h0 = pt*8;
  int tid = threadIdx.x;
  int pg = tid & 63;  int r = pg >> 3;  int w0 = (pg & 7)*8;
  int cg = tid >> 6;  int co_t = cg*6;

  float acc[6][8];
  #pragma unroll
  for (int c = 0; c < 6; ++c)
    #pragma unroll
    for (int p = 0; p < 8; ++p) acc[c][p] = 0.f;

  for (int s = 0; s < 3; ++s){
    if (s) __syncthreads();
    for (int i = tid; i < 80; i += 512){ in_lds[i/10][i%10][0] = 0.f; in_lds[i/10][i%10][65] = 0.f; }
    for (int i = tid; i < 5120; i += 512){
      int ci = i / 640; int rr = (i % 640) / 64; int w = i & 63;
      int grow = h0 - 1 + rr;
      int cig = ci0 + s*8 + ci;
      float v = 0.f;
      if (grow >= 0 && grow < 64){
        const float* src = (cig < CC) ? (rgb + (size_t)(b*CC+cig)*HW)
                                      : (tt  + (size_t)(b*CC+cig-CC)*HW);
        v = src[grow*64 + w];
      }
      in_lds[ci][rr][w+1] = v;
    }
    for (int i = tid; i < 3456; i += 512){
      int co = i % 48; int rest = i / 48; int ci = rest / 9; int tap = rest % 9;
      int cig = ci0 + s*8 + ci;
      w_lds[ci][tap][co] = cw[((size_t)(co0+co)*192 + cig)*9 + tap];
    }
    __syncthreads();
    #pragma unroll
    for (int ci = 0; ci < 8; ++ci){
      float rowv[3][10];
      #pragma unroll
      for (int rr = 0; rr < 3; ++rr){
        const float* rp = &in_lds[ci][r+rr][w0];
        float4 a = *(const float4*)rp;
        float4 bb = *(const float4*)(rp+4);
        float2 cc = *(const float2*)(rp+8);
        rowv[rr][0]=a.x; rowv[rr][1]=a.y; rowv[rr][2]=a.z; rowv[rr][3]=a.w;
        rowv[rr][4]=bb.x; rowv[rr][5]=bb.y; rowv[rr][6]=bb.z; rowv[rr][7]=bb.w;
        rowv[rr][8]=cc.x; rowv[rr][9]=cc.y;
      }
      #pragma unroll
      for (int tap = 0; tap < 9; ++tap){
        int rt = tap/3, ct = tap - rt*3;
        float2 wa = *(const float2*)&w_lds[ci][tap][co_t];
        float2 wb = *(const float2*)&w_lds[ci][tap][co_t+2];
        float2 wc = *(const float2*)&w_lds[ci][tap][co_t+4];
        float wv[6] = {wa.x, wa.y, wb.x, wb.y, wc.x, wc.y};
        #pragma unroll
        for (int p = 0; p < 8; ++p){
          float iv = rowv[rt][p + ct];
          #pragma unroll
          for (int c = 0; c < 6; ++c) acc[c][p] += wv[c]*iv;
        }
      }
    }
  }
  #pragma unroll
  for (int p = 0; p < 8; ++p){
    int pix = (h0 + r)*64 + w0 + p;
    float* o = pbuf + (((size_t)kc*2 + b)*HW + pix)*CC + co0 + co_t;
    float2 o0 = {acc[0][p], acc[1][p]};
    float2 o1 = {acc[2][p], acc[3][p]};
    float2 o2 = {acc[4][p], acc[5][p]};
    *(float2*)&o[0] = o0; *(float2*)&o[2] = o1; *(float2*)&o[4] = o2;
  }
}

// K1b: reduce 8 partials + bias + BN + ReLU + per-pixel LayerNorm -> xn (pixel-major)
__global__ void k_convred(const float* __restrict__ pbuf, const float* __restrict__ cb,
                          const float* __restrict__ bng, const float* __restrict__ bnb,
                          const float* __restrict__ bnm, const float* __restrict__ bnv,
                          const float* __restrict__ lng, const float* __restrict__ lnb,
                          float* __restrict__ xn){
  __shared__ float sm[4], sm2[4], smu[2], srs[2];
  int tid = threadIdx.x;
  int half = tid >> 7;
  int c = tid & 127;
  int pixg = blockIdx.x*2 + half;
  int b = pixg >> 12; int pix = pixg & (HW-1);
  float v = 0.f;
  if (c < CC){
    #pragma unroll
    for (int kc = 0; kc < 8; ++kc)
      v += pbuf[(((size_t)kc*2 + b)*HW + pix)*CC + c];
    v += cb[c];
    v = (v - bnm[c]) * rsqrtf(bnv[c] + 1e-5f);
    v = v * bng[c] + bnb[c];
    v = fmaxf(v, 0.f);
  }
  float s = v, s2 = v*v;
  #pragma unroll
  for (int off = 32; off; off >>= 1){ s += __shfl_down(s, off); s2 += __shfl_down(s2, off); }
  if ((tid & 63) == 0){ sm[tid>>6] = s; sm2[tid>>6] = s2; }
  __syncthreads();
  if (tid < 2){
    float ts = sm[2*tid] + sm[2*tid+1];
    float ts2 = sm2[2*tid] + sm2[2*tid+1];
    float mu = ts * (1.f/CC);
    float var = ts2 * (1.f/CC) - mu*mu;
    smu[tid] = mu; srs[tid] = rsqrtf(var + 1e-5f);
  }
  __syncthreads();
  if (c < CC)
    xn[(size_t)pixg*CC + c] = (v - smu[half])*srs[half]*lng[c] + lnb[c];
}

// K2b: xz(8192x384) = xn(8192x96) @ in_proj_w^T(96x384)
__global__ void k_inproj(const float* __restrict__ xn, const float* __restrict__ ipw,
                         float* __restrict__ xz){
  __shared__ float As[64][97];
  __shared__ __align__(16) float Bs[96][68];
  int p0 = blockIdx.x*64;
  int e0 = blockIdx.y*64;
  int tid = threadIdx.x;
  for (int idx = tid; idx < 64*96; idx += 256){
    int r = idx/96, c = idx - r*96;
    As[r][c] = xn[(size_t)(p0+r)*96 + c];
  }
  for (int idx = tid; idx < 96*64; idx += 256){
    int c = idx/64, e = idx - c*64;
    Bs[c][e] = ipw[(size_t)(e0+e)*96 + c];
  }
  __syncthreads();
  int tx = tid & 15, ty = tid >> 4;
  float acc[4][4] = {};
  for (int c = 0; c < 96; ++c){
    float a[4];
    #pragma unroll
    for (int i = 0; i < 4; ++i) a[i] = As[ty*4+i][c];
    float4 bb = *(const float4*)&Bs[c][tx*4];
    float bv[4] = {bb.x, bb.y, bb.z, bb.w};
    #pragma unroll
    for (int i = 0; i < 4; ++i)
      #pragma unroll
      for (int j = 0; j < 4; ++j) acc[i][j] += a[i]*bv[j];
  }
  for (int i = 0; i < 4; ++i){
    float4 o = {acc[i][0], acc[i][1], acc[i][2], acc[i][3]};
    *(float4*)&xz[(size_t)(p0+ty*4+i)*384 + e0 + tx*4] = o;
  }
}

// K3: depthwise 3x3 conv + bias + SiLU -> xc (B, L, 192)
__global__ void k_dwconv(const float* __restrict__ xz, const float* __restrict__ dww,
                         const float* __restrict__ dwb, float* __restrict__ xc){
  int tid = blockIdx.x*256 + threadIdx.x;
  int d  = tid % DD;
  int bp = tid / DD;
  int pix = bp & (HW-1); int b = bp >> 12;
  int h = pix >> 6, w = pix & 63;
  float acc = dwb[d];
  #pragma unroll
  for (int dh = -1; dh <= 1; ++dh){
    int hh = h + dh;
    if (hh < 0 || hh > 63) continue;
    #pragma unroll
    for (int dw = -1; dw <= 1; ++dw){
      int ww = w + dw;
      if (ww < 0 || ww > 63) continue;
      acc += xz[((size_t)b*HW + hh*64 + ww)*384 + d] * dww[d*9 + (dh+1)*3 + (dw+1)];
    }
  }
  xc[(size_t)bp*DD + d] = siluf(acc);
}

// K4: x_dbl projections. Register-tiled GEMM: per block (b,k) x 32 l.
// 128 thr = 8 cg x 16 lg; thread tile 5c x 2l (c padded 38->40).
// GEMM2 (dt-rank 6 -> 192 + softplus) fused via dts in LDS.
__global__ void __launch_bounds__(128)
k_xdbl(const float* __restrict__ xc, const float* __restrict__ xpw,
       const float* __restrict__ dtw, const float* __restrict__ dtb,
       float* __restrict__ Bsb, float* __restrict__ Csb,
       float* __restrict__ dlt){
  __shared__ float xs_lds[48*36];        // [d][l] transposed, pad 36
  __shared__ float w_lds[40*52];         // [c][d], pad 52 (16B aligned rows)
  __shared__ float dts_lds[32][8];
  int blk = blockIdx.x;
  int lt = blk & 127; int b4k = blk >> 7;
  int k = b4k & 3, b = b4k >> 2;
  int l0 = lt*32;
  int tid = threadIdx.x;
  int lg = tid & 15, cg = tid >> 4;
  int c0 = cg*5;
  float acc[5][2] = {};

  for (int chunk = 0; chunk < 4; ++chunk){
    int d0 = chunk*48;
    if (chunk) __syncthreads();
    // stage xs transposed: q-major -> conflict-free LDS writes
    #pragma unroll
    for (int i = tid; i < 384; i += 128){
      int q = i >> 5, l = i & 31;
      int lm = lmap_xs(k, l0 + l);
      float4 v = *(const float4*)&xc[((size_t)b*HW + lm)*DD + d0 + q*4];
      xs_lds[(q*4+0)*36 + l] = v.x;
      xs_lds[(q*4+1)*36 + l] = v.y;
      xs_lds[(q*4+2)*36 + l] = v.z;
      xs_lds[(q*4+3)*36 + l] = v.w;
    }
    // stage weights (38 rows used, 2 pad rows garbage-but-dead)
    for (int i = tid; i < 456; i += 128){
      int c = i / 12, q = i - (i/12)*12;
      float4 v = *(const float4*)&xpw[((size_t)(k*38 + c))*192 + d0 + q*4];
      *(float4*)&w_lds[c*52 + q*4] = v;
    }
    __syncthreads();
    #pragma unroll 2
    for (int dq = 0; dq < 12; ++dq){
      float4 wv[5];
      #pragma unroll
      for (int j = 0; j < 5; ++j)
        wv[j] = *(const float4*)&w_lds[(c0+j)*52 + dq*4];
      #pragma unroll
      for (int dd = 0; dd < 4; ++dd){
        float2 xv = *(const float2*)&xs_lds[(dq*4+dd)*36 + lg*2];
        #pragma unroll
        for (int j = 0; j < 5; ++j){
          float wc = ((const float*)&wv[j])[dd];
          acc[j][0] += wc * xv.x;
          acc[j][1] += wc * xv.y;
        }
      }
    }
  }

  // epilogue: scatter Bs/Cs, collect dts in LDS
  int lA = l0 + lg*2;
  #pragma unroll
  for (int j = 0; j < 5; ++j){
    int c = c0 + j;
    if (c < 6){
      dts_lds[lg*2  ][c] = acc[j][0];
      dts_lds[lg*2+1][c] = acc[j][1];
    } else if (c < 22){
      Bsb[((size_t)b4k*HW + lA  )*NS + (c-6)] = acc[j][0];
      Bsb[((size_t)b4k*HW + lA+1)*NS + (c-6)] = acc[j][1];
    } else if (c < 38){
      Csb[((size_t)b4k*HW + lA  )*NS + (c-22)] = acc[j][0];
      Csb[((size_t)b4k*HW + lA+1)*NS + (c-22)] = acc[j][1];
    }
  }
  __syncthreads();

  // GEMM2: delta = softplus(dts @ dtw^T + dtb); each thread's d cycles over 3 values
  float dtw_r0[6], dtw_r1[6], dtw_r2[6];
  int dv0 = tid % 192, dv1 = (tid + 128) % 192, dv2 = (tid + 256) % 192;
  float dtb0 = dtb[k*DD + dv0], dtb1 = dtb[k*DD + dv1], dtb2 = dtb[k*DD + dv2];
  #pragma unroll
  for (int r = 0; r < 6; ++r){
    dtw_r0[r] = dtw[((size_t)(k*DD + dv0))*6 + r];
    dtw_r1[r] = dtw[((size_t)(k*DD + dv1))*6 + r];
    dtw_r2[r] = dtw[((size_t)(k*DD + dv2))*6 + r];
  }
  for (int it3 = 0; it3 < 16; ++it3){
    {
      int o = tid + (it3*3+0)*128; int l = o / 192;
      float4 t0 = *(const float4*)&dts_lds[l][0];
      float2 t1 = *(const float2*)&dts_lds[l][4];
      float s = dtb0 + t0.x*dtw_r0[0] + t0.y*dtw_r0[1] + t0.z*dtw_r0[2]
                     + t0.w*dtw_r0[3] + t1.x*dtw_r0[4] + t1.y*dtw_r0[5];
      dlt[((size_t)b4k*HW + l0 + l)*DD + dv0] = softplusf(s);
    }
    {
      int o = tid + (it3*3+1)*128; int l = o / 192;
      float4 t0 = *(const float4*)&dts_lds[l][0];
      float2 t1 = *(const float2*)&dts_lds[l][4];
      float s = dtb1 + t0.x*dtw_r1[0] + t0.y*dtw_r1[1] + t0.z*dtw_r1[2]
                     + t0.w*dtw_r1[3] + t1.x*dtw_r1[4] + t1.y*dtw_r1[5];
      dlt[((size_t)b4k*HW + l0 + l)*DD + dv1] = softplusf(s);
    }
    {
      int o = tid + (it3*3+2)*128; int l = o / 192;
      float4 t0 = *(const float4*)&dts_lds[l][0];
      float2 t1 = *(const float2*)&dts_lds[l][4];
      float s = dtb2 + t0.x*dtw_r2[0] + t0.y*dtw_r2[1] + t0.z*dtw_r2[2]
                     + t0.w*dtw_r2[3] + t1.x*dtw_r2[4] + t1.y*dtw_r2[5];
      dlt[((size_t)b4k*HW + l0 + l)*DD + dv2] = softplusf(s);
    }
  }
}

// K5a: per-chunk scan summaries. n-split: thread owns (b4k, chunk, d, ng) = 4 states.
__global__ void k_scan1(const float* __restrict__ dlt, const float* __restrict__ xc,
                        const float* __restrict__ Bsb, const float* __restrict__ Alog,
                        float* __restrict__ Ac, float* __restrict__ Bc){
  int tid = blockIdx.x*256 + threadIdx.x;
  int ng = tid & 3;
  int t2 = tid >> 2;
  int d = t2 % DD;
  int rest = t2 / DD;
  int chunk = rest & (NC-1);
  int b4k = rest >> 6;
  int k = b4k & 3, b = b4k >> 2;
  float4 Af = *(const float4*)&Alog[(size_t)(k*DD+d)*NS + ng*4];
  float Av[4] = {-expf(Af.x), -expf(Af.y), -expf(Af.z), -expf(Af.w)};
  float h[4] = {0.f,0.f,0.f,0.f};
  float ap[4] = {1.f,1.f,1.f,1.f};
  int l0 = chunk*LC;
  const float* dp  = dlt + ((size_t)b4k*HW + l0)*DD + d;
  const float4* Bp4 = (const float4*)(Bsb + ((size_t)b4k*HW + l0)*NS) + ng;
  const float* xcb = xc + (size_t)b*HW*DD + d;
  float dvc = dp[0];
  float xvc = xcb[(size_t)lmap_xs(k, l0)*DD];
  float4 Bvc = Bp4[0];
  #pragma unroll 4
  for (int i = 0; i < LC; ++i){
    float dvn = 0.f, xvn = 0.f; float4 Bvn = {0.f,0.f,0.f,0.f};
    if (i+1 < LC){
      dvn = dp[(size_t)(i+1)*DD];
      xvn = xcb[(size_t)lmap_xs(k, l0+i+1)*DD];
      Bvn = Bp4[(size_t)(i+1)*4];
    }
    float du = dvc*xvc;
    float a0 = __expf(dvc*Av[0]), a1 = __expf(dvc*Av[1]),
          a2 = __expf(dvc*Av[2]), a3 = __expf(dvc*Av[3]);
    h[0] = h[0]*a0 + du*Bvc.x; ap[0] *= a0;
    h[1] = h[1]*a1 + du*Bvc.y; ap[1] *= a1;
    h[2] = h[2]*a2 + du*Bvc.z; ap[2] *= a2;
    h[3] = h[3]*a3 + du*Bvc.w; ap[3] *= a3;
    dvc = dvn; xvc = xvn; Bvc = Bvn;
  }
  size_t base = (size_t)chunk*NCH + (size_t)(b4k*DD + d)*NS + ng*4;
  *(float4*)&Ac[base] = make_float4(ap[0],ap[1],ap[2],ap[3]);
  *(float4*)&Bc[base] = make_float4(h[0],h[1],h[2],h[3]);
}

// K5b: sequential prefix over chunk summaries; writes incoming state IN-PLACE over Ac.
__global__ void k_scan2(float* __restrict__ Ac, const float* __restrict__ Bc){
  int chain = blockIdx.x*256 + threadIdx.x;
  float h = 0.f;
  for (int c = 0; c < NC; ++c){
    size_t idx = (size_t)c*NCH + chain;
    float a = Ac[idx], bv = Bc[idx];
    Ac[idx] = h;
    h = a*h + bv;
  }
}

// K5c: re-run chunks with correct h0 (hst == Ac buffer), emit ys. n-split + prefetch.
__global__ void k_scan3(const float* __restrict__ dlt, const float* __restrict__ xc,
                        const float* __restrict__ Bsb, const float* __restrict__ Csb,
                        const float* __restrict__ Alog, const float* __restrict__ hst,
                        float* __restrict__ ys){
  int tid = blockIdx.x*256 + threadIdx.x;
  int ng = tid & 3;
  int t2 = tid >> 2;
  int d = t2 % DD;
  int rest = t2 / DD;
  int chunk = rest & (NC-1);
  int b4k = rest >> 6;
  int k = b4k & 3, b = b4k >> 2;
  float4 Af = *(const float4*)&Alog[(size_t)(k*DD+d)*NS + ng*4];
  float Av[4] = {-expf(Af.x), -expf(Af.y), -expf(Af.z), -expf(Af.w)};
  size_t hbase = (size_t)chunk*NCH + (size_t)(b4k*DD + d)*NS + ng*4;
  float4 hf = *(const float4*)&hst[hbase];
  float h[4] = {hf.x, hf.y, hf.z, hf.w};
  int l0 = chunk*LC;
  const float* dp  = dlt + ((size_t)b4k*HW + l0)*DD + d;
  const float4* Bp4 = (const float4*)(Bsb + ((size_t)b4k*HW + l0)*NS) + ng;
  const float4* Cp4 = (const float4*)(Csb + ((size_t)b4k*HW + l0)*NS) + ng;
  const float* xcb = xc + (size_t)b*HW*DD + d;
  float* yp = ys + ((size_t)b4k*HW + l0)*DD + d;
  float dvc = dp[0];
  float xvc = xcb[(size_t)lmap_xs(k, l0)*DD];
  float4 Bvc = Bp4[0];
  float4 Cvc = Cp4[0];
  #pragma unroll 4
  for (int i = 0; i < LC; ++i){
    float dvn = 0.f, xvn = 0.f; float4 Bvn = {0.f,0.f,0.f,0.f}, Cvn = {0.f,0.f,0.f,0.f};
    if (i+1 < LC){
      dvn = dp[(size_t)(i+1)*DD];
      xvn = xcb[(size_t)lmap_xs(k, l0+i+1)*DD];
      Bvn = Bp4[(size_t)(i+1)*4];
      Cvn = Cp4[(size_t)(i+1)*4];
    }
    float du = dvc*xvc;
    float a0 = __expf(dvc*Av[0]), a1 = __expf(dvc*Av[1]),
          a2 = __expf(dvc*Av[2]), a3 = __expf(dvc*Av[3]);
    h[0] = h[0]*a0 + du*Bvc.x;
    h[1] = h[1]*a1 + du*Bvc.y;
    h[2] = h[2]*a2 + du*Bvc.z;
    h[3] = h[3]*a3 + du*Bvc.w;
    float y = h[0]*Cvc.x + h[1]*Cvc.y + h[2]*Cvc.z + h[3]*Cvc.w;
    y += __shfl_xor(y, 1, 4);
    y += __shfl_xor(y, 2, 4);
    if (ng == 0) yp[(size_t)i*DD] = y;
    dvc = dvn; xvc = xvn; Bvc = Bvn; Cvc = Cvn;
  }
}

// K6a: merge 4 dirs + D*xs skip, LN over 192, *silu(z) -> yg (B,L,192). Wave per pixel.
__global__ void k_gate(const float* __restrict__ ys, const float* __restrict__ xc,
                       const float* __restrict__ Ds, const float* __restrict__ xz,
                       const float* __restrict__ ong, const float* __restrict__ onb,
                       float* __restrict__ yg){
  int gt = blockIdx.x*256 + threadIdx.x;
  int wave = gt >> 6;                // global pixel index (b*HW + l)
  int lane = gt & 63;
  int b = wave >> 12; int l = wave & (HW-1);
  int l1 = ((l & 63) << 6) | (l >> 6);
  size_t base = (size_t)b*KK*HW*DD;
  float v[3]; float s = 0.f, s2 = 0.f;
  #pragma unroll
  for (int j = 0; j < 3; ++j){
    int d = lane + j*64;
    float t;
    t  = ys[base + ((size_t)0*HW + l        )*DD + d];
    t += ys[base + ((size_t)1*HW + l1       )*DD + d];
    t += ys[base + ((size_t)2*HW + (HW-1-l ))*DD + d];
    t += ys[base + ((size_t)3*HW + (HW-1-l1))*DD + d];
    t += xc[((size_t)b*HW + l)*DD + d] * (Ds[d] + Ds[DD+d] + Ds[2*DD+d] + Ds[3*DD+d]);
    v[j] = t; s += t; s2 += t*t;
  }
  #pragma unroll
  for (int off = 32; off; off >>= 1){ s += __shfl_xor(s, off); s2 += __shfl_xor(s2, off); }
  float mu = s*(1.f/DD);
  float rstd = rsqrtf(s2*(1.f/DD) - mu*mu + 1e-5f);
  #pragma unroll
  for (int j = 0; j < 3; ++j){
    int d = lane + j*64;
    float z = xz[((size_t)b*HW + l)*384 + DD + d];
    float x = (v[j]-mu)*rstd*ong[d] + onb[d];
    yg[(size_t)wave*DD + d] = x * siluf(z);
  }
}

// K6b: out = yg(8192x192) @ opw^T(192x96), NCHW write. 32px x 96c per block.
__global__ void k_outproj(const float* __restrict__ yg, const float* __restrict__ opw,
                          float* __restrict__ out){
  __shared__ float yl[48][36];   // [k][px], pad
  __shared__ float wl[48][97];   // [k][c], pad
  int blk = blockIdx.x;          // b*128 + pt
  int b = blk >> 7; int pt = blk & 127;
  int px0 = pt*32;
  int tid = threadIdx.x;
  int pxg = tid & 7;             // 8 groups x 4 px
  int cgi = tid >> 3;            // 32 groups x 3 c
  float acc[4][3] = {};
  for (int k0 = 0; k0 < DD; k0 += 48){
    if (k0) __syncthreads();
    for (int i = tid; i < 32*48; i += 256){
      int r = i/48, k = i - r*48;
      yl[k][r] = yg[((size_t)b*HW + px0 + r)*DD + k0 + k];
    }
    for (int i = tid; i < 96*48; i += 256){
      int c = i/48, k = i - c*48;
      wl[k][c] = opw[(size_t)c*DD + k0 + k];
    }
    __syncthreads();
    #pragma unroll 4
    for (int k = 0; k < 48; ++k){
      float4 yv = *(const float4*)&yl[k][pxg*4];
      float w0 = wl[k][cgi*3], w1 = wl[k][cgi*3+1], w2 = wl[k][cgi*3+2];
      acc[0][0] += yv.x*w0; acc[0][1] += yv.x*w1; acc[0][2] += yv.x*w2;
      acc[1][0] += yv.y*w0; acc[1][1] += yv.y*w1; acc[1][2] += yv.y*w2;
      acc[2][0] += yv.z*w0; acc[2][1] += yv.z*w1; acc[2][2] += yv.z*w2;
      acc[3][0] += yv.w*w0; acc[3][1] += yv.w*w1; acc[3][2] += yv.w*w2;
    }
  }
  #pragma unroll
  for (int j = 0; j < 3; ++j){
    int c = cgi*3 + j;
    float4 o = {acc[0][j], acc[1][j], acc[2][j], acc[3][j]};
    *(float4*)&out[((size_t)b*CC + c)*HW + px0 + pxg*4] = o;
  }
}

extern "C" void kernel_launch(void* const* d_in, const int* in_sizes, int n_in,
                              void* d_out, int out_size, void* d_ws, size_t ws_size,
                              hipStream_t stream) {
  const float* rgb   = (const float*)d_in[0];
  const float* tt    = (const float*)d_in[1];
  const float* cw    = (const float*)d_in[2];
  const float* cb    = (const float*)d_in[3];
  const float* bng   = (const float*)d_in[4];
  const float* bnb   = (const float*)d_in[5];
  const float* bnm   = (const float*)d_in[6];
  const float* bnv   = (const float*)d_in[7];
  const float* lng   = (const float*)d_in[8];
  const float* lnb   = (const float*)d_in[9];
  const float* ipw   = (const float*)d_in[10];
  const float* dww   = (const float*)d_in[11];
  const float* dwb   = (const float*)d_in[12];
  const float* xpw   = (const float*)d_in[13];
  const float* dtw   = (const float*)d_in[14];
  const float* dtb   = (const float*)d_in[15];
  const float* Alog  = (const float*)d_in[16];
  const float* Ds    = (const float*)d_in[17];
  const float* ong   = (const float*)d_in[18];
  const float* onb   = (const float*)d_in[19];
  const float* opw   = (const float*)d_in[20];
  float* out = (float*)d_out;

  float* ws = (float*)d_ws;
  // persistent regions:
  float* xn   = ws + 786432;                 // 786432 (pixel-major, post-LN)
  float* xz   = ws + 1572864;                // 3145728
  float* xc   = ws + 4718592;                // 1572864
  float* Bsb  = ws + 6291456;                // 524288
  float* Csb  = ws + 6815744;                // 524288
  float* dlt  = ws + 7340032;                // 6291456
  float* ysb  = ws + 13631488;               // 6291456  (end 19922944 floats ~76MB)
  // transient overlays:
  float* pbuf = ws + 1572864;                // 6291456 (xz..dlt-front; dead before k_inproj)
  float* Ac   = ws;                          // 1572864 (conv/xn region; xn dead after inproj)
  float* Bc   = ysb;                         // 1572864 (front of ysb; dead before k_scan3 writes ys)
  float* yg   = ws + 7340032;                // 1572864 (over dlt; dlt dead after k_scan3)
  // k_scan2 writes hst in-place over Ac; k_scan3 reads it from there.

  k_conv1<<<256, 512, 0, stream>>>(rgb, tt, cw, pbuf);
  k_convred<<<4096, 256, 0, stream>>>(pbuf, cb, bng, bnb, bnm, bnv, lng, lnb, xn);
  dim3 g2(128, 6);
  k_inproj<<<g2, 256, 0, stream>>>(xn, ipw, xz);
  k_dwconv<<<6144, 256, 0, stream>>>(xz, dww, dwb, xc);
  k_xdbl<<<1024, 128, 0, stream>>>(xc, xpw, dtw, dtb, Bsb, Csb, dlt);
  k_scan1<<<1536, 256, 0, stream>>>(dlt, xc, Bsb, Alog, Ac, Bc);
  k_scan2<<<96, 256, 0, stream>>>(Ac, Bc);
  k_scan3<<<1536, 256, 0, stream>>>(dlt, xc, Bsb, Csb, Alog, Ac, ysb);
  k_gate<<<2048, 256, 0, stream>>>(ysb, xc, Ds, xz, ong, onb, yg);
  k_outproj<<<256, 256, 0, stream>>>(yg, opw, out);
}

// Round 7
// 255.787 us; speedup vs baseline: 10.2901x; 1.0106x over previous
//
#include <hip/hip_runtime.h>
#include <math.h>

#define HW 4096
#define CC 96
#define DD 192
#define NS 16
#define KK 4
#define LC 64
#define NC 64
#define NCH (8*DD*NS)   // 24576 chains

__device__ __forceinline__ float siluf(float x){ return x / (1.f + expf(-x)); }
__device__ __forceinline__ float softplusf(float x){ return (x > 20.f) ? x : log1pf(expf(x)); }
__device__ __forceinline__ float softplus_fast(float x){ return (x > 20.f) ? x : log1pf(__expf(x)); }

__device__ __forceinline__ int lmap_xs(int k, int l){
  if (k == 1) return ((l & 63) << 6) | (l >> 6);
  if (k == 2) return (HW - 1) - l;
  if (k == 3) { int r = (HW - 1) - l; return ((r & 63) << 6) | (r >> 6); }
  return l;
}

// K1: conv3x3(192->96) partials, K-split over ci.
__global__ void __launch_bounds__(512, 2)
k_conv1(const float* __restrict__ rgb, const float* __restrict__ tt,
        const float* __restrict__ cw, float* __restrict__ pbuf){
  __shared__ float in_lds[8][10][68];
  __shared__ float w_lds[8][9][48];
  int bi = blockIdx.x;
  int kc  = bi & 7;        int ci0 = kc*24;
  int r2  = bi >> 3;
  int cog = r2 & 1;        int co0 = cog*48;
  int r3  = r2 >> 1;
  int b   = r3 & 1;
  int pt  = r3 >> 1;       int h0 = pt*8;
  int tid = threadIdx.x;
  int pg = tid & 63;  int r = pg >> 3;  int w0 = (pg & 7)*8;
  int cg = tid >> 6;  int co_t = cg*6;

  float acc[6][8];
  #pragma unroll
  for (int c = 0; c < 6; ++c)
    #pragma unroll
    for (int p = 0; p < 8; ++p) acc[c][p] = 0.f;

  for (int s = 0; s < 3; ++s){
    if (s) __syncthreads();
    for (int i = tid; i < 80; i += 512){ in_lds[i/10][i%10][0] = 0.f; in_lds[i/10][i%10][65] = 0.f; }
    for (int i = tid; i < 5120; i += 512){
      int ci = i / 640; int rr = (i % 640) / 64; int w = i & 63;
      int grow = h0 - 1 + rr;
      int cig = ci0 + s*8 + ci;
      float v = 0.f;
      if (grow >= 0 && grow < 64){
        const float* src = (cig < CC) ? (rgb + (size_t)(b*CC+cig)*HW)
                                      : (tt  + (size_t)(b*CC+cig-CC)*HW);
        v = src[grow*64 + w];
      }
      in_lds[ci][rr][w+1] = v;
    }
    for (int i = tid; i < 3456; i += 512){
      int co = i % 48; int rest = i / 48; int ci = rest / 9; int tap = rest % 9;
      int cig = ci0 + s*8 + ci;
      w_lds[ci][tap][co] = cw[((size_t)(co0+co)*192 + cig)*9 + tap];
    }
    __syncthreads();
    #pragma unroll
    for (int ci = 0; ci < 8; ++ci){
      float rowv[3][10];
      #pragma unroll
      for (int rr = 0; rr < 3; ++rr){
        const float* rp = &in_lds[ci][r+rr][w0];
        float4 a = *(const float4*)rp;
        float4 bb = *(const float4*)(rp+4);
        float2 cc = *(const float2*)(rp+8);
        rowv[rr][0]=a.x; rowv[rr][1]=a.y; rowv[rr][2]=a.z; rowv[rr][3]=a.w;
        rowv[rr][4]=bb.x; rowv[rr][5]=bb.y; rowv[rr][6]=bb.z; rowv[rr][7]=bb.w;
        rowv[rr][8]=cc.x; rowv[rr][9]=cc.y;
      }
      #pragma unroll
      for (int tap = 0; tap < 9; ++tap){
        int rt = tap/3, ct = tap - rt*3;
        float2 wa = *(const float2*)&w_lds[ci][tap][co_t];
        float2 wb = *(const float2*)&w_lds[ci][tap][co_t+2];
        float2 wc = *(const float2*)&w_lds[ci][tap][co_t+4];
        float wv[6] = {wa.x, wa.y, wb.x, wb.y, wc.x, wc.y};
        #pragma unroll
        for (int p = 0; p < 8; ++p){
          float iv = rowv[rt][p + ct];
          #pragma unroll
          for (int c = 0; c < 6; ++c) acc[c][p] += wv[c]*iv;
        }
      }
    }
  }
  #pragma unroll
  for (int p = 0; p < 8; ++p){
    int pix = (h0 + r)*64 + w0 + p;
    float* o = pbuf + (((size_t)kc*2 + b)*HW + pix)*CC + co0 + co_t;
    float2 o0 = {acc[0][p], acc[1][p]};
    float2 o1 = {acc[2][p], acc[3][p]};
    float2 o2 = {acc[4][p], acc[5][p]};
    *(float2*)&o[0] = o0; *(float2*)&o[2] = o1; *(float2*)&o[4] = o2;
  }
}

// K1b: reduce 8 partials + bias + BN + ReLU + per-pixel LayerNorm -> xn (pixel-major)
__global__ void k_convred(const float* __restrict__ pbuf, const float* __restrict__ cb,
                          const float* __restrict__ bng, const float* __restrict__ bnb,
                          const float* __restrict__ bnm, const float* __restrict__ bnv,
                          const float* __restrict__ lng, const float* __restrict__ lnb,
                          float* __restrict__ xn){
  __shared__ float sm[4], sm2[4], smu[2], srs[2];
  int tid = threadIdx.x;
  int half = tid >> 7;
  int c = tid & 127;
  int pixg = blockIdx.x*2 + half;
  int b = pixg >> 12; int pix = pixg & (HW-1);
  float v = 0.f;
  if (c < CC){
    #pragma unroll
    for (int kc = 0; kc < 8; ++kc)
      v += pbuf[(((size_t)kc*2 + b)*HW + pix)*CC + c];
    v += cb[c];
    v = (v - bnm[c]) * rsqrtf(bnv[c] + 1e-5f);
    v = v * bng[c] + bnb[c];
    v = fmaxf(v, 0.f);
  }
  float s = v, s2 = v*v;
  #pragma unroll
  for (int off = 32; off; off >>= 1){ s += __shfl_down(s, off); s2 += __shfl_down(s2, off); }
  if ((tid & 63) == 0){ sm[tid>>6] = s; sm2[tid>>6] = s2; }
  __syncthreads();
  if (tid < 2){
    float ts = sm[2*tid] + sm[2*tid+1];
    float ts2 = sm2[2*tid] + sm2[2*tid+1];
    float mu = ts * (1.f/CC);
    float var = ts2 * (1.f/CC) - mu*mu;
    smu[tid] = mu; srs[tid] = rsqrtf(var + 1e-5f);
  }
  __syncthreads();
  if (c < CC)
    xn[(size_t)pixg*CC + c] = (v - smu[half])*srs[half]*lng[c] + lnb[c];
}

// K2b: xz(8192x384) = xn(8192x96) @ in_proj_w^T(96x384)
__global__ void k_inproj(const float* __restrict__ xn, const float* __restrict__ ipw,
                         float* __restrict__ xz){
  __shared__ float As[64][97];
  __shared__ __align__(16) float Bs[96][68];
  int p0 = blockIdx.x*64;
  int e0 = blockIdx.y*64;
  int tid = threadIdx.x;
  for (int idx = tid; idx < 64*96; idx += 256){
    int r = idx/96, c = idx - r*96;
    As[r][c] = xn[(size_t)(p0+r)*96 + c];
  }
  for (int idx = tid; idx < 96*64; idx += 256){
    int c = idx/64, e = idx - c*64;
    Bs[c][e] = ipw[(size_t)(e0+e)*96 + c];
  }
  __syncthreads();
  int tx = tid & 15, ty = tid >> 4;
  float acc[4][4] = {};
  for (int c = 0; c < 96; ++c){
    float a[4];
    #pragma unroll
    for (int i = 0; i < 4; ++i) a[i] = As[ty*4+i][c];
    float4 bb = *(const float4*)&Bs[c][tx*4];
    float bv[4] = {bb.x, bb.y, bb.z, bb.w};
    #pragma unroll
    for (int i = 0; i < 4; ++i)
      #pragma unroll
      for (int j = 0; j < 4; ++j) acc[i][j] += a[i]*bv[j];
  }
  for (int i = 0; i < 4; ++i){
    float4 o = {acc[i][0], acc[i][1], acc[i][2], acc[i][3]};
    *(float4*)&xz[(size_t)(p0+ty*4+i)*384 + e0 + tx*4] = o;
  }
}

// K3: depthwise 3x3 conv + bias + SiLU -> xc (B, L, 192)
__global__ void k_dwconv(const float* __restrict__ xz, const float* __restrict__ dww,
                         const float* __restrict__ dwb, float* __restrict__ xc){
  int tid = blockIdx.x*256 + threadIdx.x;
  int d  = tid % DD;
  int bp = tid / DD;
  int pix = bp & (HW-1); int b = bp >> 12;
  int h = pix >> 6, w = pix & 63;
  float acc = dwb[d];
  #pragma unroll
  for (int dh = -1; dh <= 1; ++dh){
    int hh = h + dh;
    if (hh < 0 || hh > 63) continue;
    #pragma unroll
    for (int dw = -1; dw <= 1; ++dw){
      int ww = w + dw;
      if (ww < 0 || ww > 63) continue;
      acc += xz[((size_t)b*HW + hh*64 + ww)*384 + d] * dww[d*9 + (dh+1)*3 + (dw+1)];
    }
  }
  xc[(size_t)bp*DD + d] = siluf(acc);
}

// K4 v3: x_dbl projections. Block = (b4k, 64 px), 192 thr = 12 cg x 16 lg,
// thread tile 4c x 4l (c padded 38->48). Both operands transposed in LDS ->
// conflict-free b128 reads. xs staged once; w per-48d chunk. GEMM2 fused,
// static thread mapping (no div/mod).
__global__ void __launch_bounds__(192)
k_xdbl(const float* __restrict__ xc, const float* __restrict__ xpw,
       const float* __restrict__ dtw, const float* __restrict__ dtb,
       float* __restrict__ Bsb, float* __restrict__ Csb,
       float* __restrict__ dlt){
  __shared__ float xs_t[192*68];     // [d][l], pad 68
  __shared__ float w_t[48*52];       // [dd][c], pad 52
  __shared__ float dts_s[64][8];
  int blk = blockIdx.x;
  int lt = blk & 63; int b4k = blk >> 6;
  int k = b4k & 3, b = b4k >> 2;
  int l0 = lt*64;
  int tid = threadIdx.x;
  int lg = tid & 15, cg = tid >> 4;     // cg 0..11
  int c0 = cg*4;

  // stage xs transposed (once): thread owns one l, 16 quads
  {
    int l = tid & 63;                    // wait: 192 thr -> 3 q-groups of 64 l
    int qb = (tid >> 6) * 16;            // 0,16,32
    int lm = lmap_xs(k, l0 + l);
    const float* src = &xc[((size_t)b*HW + lm)*DD];
    #pragma unroll
    for (int q = 0; q < 16; ++q){
      float4 v = *(const float4*)&src[(qb+q)*4];
      xs_t[((qb+q)*4+0)*68 + l] = v.x;
      xs_t[((qb+q)*4+1)*68 + l] = v.y;
      xs_t[((qb+q)*4+2)*68 + l] = v.z;
      xs_t[((qb+q)*4+3)*68 + l] = v.w;
    }
  }

  float acc[4][4] = {};
  for (int ch = 0; ch < 4; ++ch){
    __syncthreads();
    // stage w chunk transposed: 38 c x 48 d
    for (int i = tid; i < 456; i += 192){
      int c = i/12, q = i - (i/12)*12;
      float4 v = *(const float4*)&xpw[((size_t)(k*38 + c))*192 + ch*48 + q*4];
      w_t[(q*4+0)*52 + c] = v.x;
      w_t[(q*4+1)*52 + c] = v.y;
      w_t[(q*4+2)*52 + c] = v.z;
      w_t[(q*4+3)*52 + c] = v.w;
    }
    __syncthreads();
    const float* xbase = &xs_t[(ch*48)*68 + lg*4];
    #pragma unroll 4
    for (int dd = 0; dd < 48; ++dd){
      float4 wv = *(const float4*)&w_t[dd*52 + c0];
      float4 xv = *(const float4*)&xbase[dd*68];
      acc[0][0] += wv.x*xv.x; acc[0][1] += wv.x*xv.y; acc[0][2] += wv.x*xv.z; acc[0][3] += wv.x*xv.w;
      acc[1][0] += wv.y*xv.x; acc[1][1] += wv.y*xv.y; acc[1][2] += wv.y*xv.z; acc[1][3] += wv.y*xv.w;
      acc[2][0] += wv.z*xv.x; acc[2][1] += wv.z*xv.y; acc[2][2] += wv.z*xv.z; acc[2][3] += wv.z*xv.w;
      acc[3][0] += wv.w*xv.x; acc[3][1] += wv.w*xv.y; acc[3][2] += wv.w*xv.z; acc[3][3] += wv.w*xv.w;
    }
  }

  // epilogue scatter: dts -> LDS, Bs/Cs -> global
  #pragma unroll
  for (int j = 0; j < 4; ++j){
    int c = c0 + j;
    if (c < 6){
      #pragma unroll
      for (int i = 0; i < 4; ++i) dts_s[lg*4+i][c] = acc[j][i];
    } else if (c < 22){
      #pragma unroll
      for (int i = 0; i < 4; ++i)
        Bsb[((size_t)b4k*HW + l0 + lg*4 + i)*NS + (c-6)] = acc[j][i];
    } else if (c < 38){
      #pragma unroll
      for (int i = 0; i < 4; ++i)
        Csb[((size_t)b4k*HW + l0 + lg*4 + i)*NS + (c-22)] = acc[j][i];
    }
  }
  __syncthreads();

  // GEMM2: dlt = softplus(dts @ dtw^T + dtb). thread = (l = tid&63, dg = tid>>6)
  {
    int l = tid & 63;
    int dg = tid >> 6;          // 0..2 -> d in [dg*64, dg*64+64)
    float t0 = dts_s[l][0], t1 = dts_s[l][1], t2 = dts_s[l][2],
          t3 = dts_s[l][3], t4 = dts_s[l][4], t5 = dts_s[l][5];
    float* op = &dlt[((size_t)b4k*HW + l0 + l)*DD + dg*64];
    const float* wp = &dtw[((size_t)(k*DD + dg*64))*6];
    const float* bp2 = &dtb[k*DD + dg*64];
    #pragma unroll 4
    for (int dd = 0; dd < 64; ++dd){
      float2 wa = *(const float2*)&wp[dd*6];
      float2 wb = *(const float2*)&wp[dd*6+2];
      float2 wc = *(const float2*)&wp[dd*6+4];
      float s = bp2[dd] + t0*wa.x + t1*wa.y + t2*wb.x + t3*wb.y + t4*wc.x + t5*wc.y;
      op[dd] = softplus_fast(s);
    }
  }
}

// K5a: per-chunk scan summaries. n-split: thread owns (b4k, chunk, d, ng) = 4 states.
__global__ void k_scan1(const float* __restrict__ dlt, const float* __restrict__ xc,
                        const float* __restrict__ Bsb, const float* __restrict__ Alog,
                        float* __restrict__ Ac, float* __restrict__ Bc){
  int tid = blockIdx.x*256 + threadIdx.x;
  int ng = tid & 3;
  int t2 = tid >> 2;
  int d = t2 % DD;
  int rest = t2 / DD;
  int chunk = rest & (NC-1);
  int b4k = rest >> 6;
  int k = b4k & 3, b = b4k >> 2;
  float4 Af = *(const float4*)&Alog[(size_t)(k*DD+d)*NS + ng*4];
  float Av[4] = {-expf(Af.x), -expf(Af.y), -expf(Af.z), -expf(Af.w)};
  float h[4] = {0.f,0.f,0.f,0.f};
  float ap[4] = {1.f,1.f,1.f,1.f};
  int l0 = chunk*LC;
  const float* dp  = dlt + ((size_t)b4k*HW + l0)*DD + d;
  const float4* Bp4 = (const float4*)(Bsb + ((size_t)b4k*HW + l0)*NS) + ng;
  const float* xcb = xc + (size_t)b*HW*DD + d;
  float dvc = dp[0];
  float xvc = xcb[(size_t)lmap_xs(k, l0)*DD];
  float4 Bvc = Bp4[0];
  #pragma unroll 4
  for (int i = 0; i < LC; ++i){
    float dvn = 0.f, xvn = 0.f; float4 Bvn = {0.f,0.f,0.f,0.f};
    if (i+1 < LC){
      dvn = dp[(size_t)(i+1)*DD];
      xvn = xcb[(size_t)lmap_xs(k, l0+i+1)*DD];
      Bvn = Bp4[(size_t)(i+1)*4];
    }
    float du = dvc*xvc;
    float a0 = __expf(dvc*Av[0]), a1 = __expf(dvc*Av[1]),
          a2 = __expf(dvc*Av[2]), a3 = __expf(dvc*Av[3]);
    h[0] = h[0]*a0 + du*Bvc.x; ap[0] *= a0;
    h[1] = h[1]*a1 + du*Bvc.y; ap[1] *= a1;
    h[2] = h[2]*a2 + du*Bvc.z; ap[2] *= a2;
    h[3] = h[3]*a3 + du*Bvc.w; ap[3] *= a3;
    dvc = dvn; xvc = xvn; Bvc = Bvn;
  }
  size_t base = (size_t)chunk*NCH + (size_t)(b4k*DD + d)*NS + ng*4;
  *(float4*)&Ac[base] = make_float4(ap[0],ap[1],ap[2],ap[3]);
  *(float4*)&Bc[base] = make_float4(h[0],h[1],h[2],h[3]);
}

// K5b: sequential prefix over chunk summaries; writes incoming state IN-PLACE over Ac.
__global__ void k_scan2(float* __restrict__ Ac, const float* __restrict__ Bc){
  int chain = blockIdx.x*256 + threadIdx.x;
  float h = 0.f;
  for (int c = 0; c < NC; ++c){
    size_t idx = (size_t)c*NCH + chain;
    float a = Ac[idx], bv = Bc[idx];
    Ac[idx] = h;
    h = a*h + bv;
  }
}

// K5c: re-run chunks with correct h0 (hst == Ac buffer), emit ys. n-split + prefetch.
__global__ void k_scan3(const float* __restrict__ dlt, const float* __restrict__ xc,
                        const float* __restrict__ Bsb, const float* __restrict__ Csb,
                        const float* __restrict__ Alog, const float* __restrict__ hst,
                        float* __restrict__ ys){
  int tid = blockIdx.x*256 + threadIdx.x;
  int ng = tid & 3;
  int t2 = tid >> 2;
  int d = t2 % DD;
  int rest = t2 / DD;
  int chunk = rest & (NC-1);
  int b4k = rest >> 6;
  int k = b4k & 3, b = b4k >> 2;
  float4 Af = *(const float4*)&Alog[(size_t)(k*DD+d)*NS + ng*4];
  float Av[4] = {-expf(Af.x), -expf(Af.y), -expf(Af.z), -expf(Af.w)};
  size_t hbase = (size_t)chunk*NCH + (size_t)(b4k*DD + d)*NS + ng*4;
  float4 hf = *(const float4*)&hst[hbase];
  float h[4] = {hf.x, hf.y, hf.z, hf.w};
  int l0 = chunk*LC;
  const float* dp  = dlt + ((size_t)b4k*HW + l0)*DD + d;
  const float4* Bp4 = (const float4*)(Bsb + ((size_t)b4k*HW + l0)*NS) + ng;
  const float4* Cp4 = (const float4*)(Csb + ((size_t)b4k*HW + l0)*NS) + ng;
  const float* xcb = xc + (size_t)b*HW*DD + d;
  float* yp = ys + ((size_t)b4k*HW + l0)*DD + d;
  float dvc = dp[0];
  float xvc = xcb[(size_t)lmap_xs(k, l0)*DD];
  float4 Bvc = Bp4[0];
  float4 Cvc = Cp4[0];
  #pragma unroll 4
  for (int i = 0; i < LC; ++i){
    float dvn = 0.f, xvn = 0.f; float4 Bvn = {0.f,0.f,0.f,0.f}, Cvn = {0.f,0.f,0.f,0.f};
    if (i+1 < LC){
      dvn = dp[(size_t)(i+1)*DD];
      xvn = xcb[(size_t)lmap_xs(k, l0+i+1)*DD];
      Bvn = Bp4[(size_t)(i+1)*4];
      Cvn = Cp4[(size_t)(i+1)*4];
    }
    float du = dvc*xvc;
    float a0 = __expf(dvc*Av[0]), a1 = __expf(dvc*Av[1]),
          a2 = __expf(dvc*Av[2]), a3 = __expf(dvc*Av[3]);
    h[0] = h[0]*a0 + du*Bvc.x;
    h[1] = h[1]*a1 + du*Bvc.y;
    h[2] = h[2]*a2 + du*Bvc.z;
    h[3] = h[3]*a3 + du*Bvc.w;
    float y = h[0]*Cvc.x + h[1]*Cvc.y + h[2]*Cvc.z + h[3]*Cvc.w;
    y += __shfl_xor(y, 1, 4);
    y += __shfl_xor(y, 2, 4);
    if (ng == 0) yp[(size_t)i*DD] = y;
    dvc = dvn; xvc = xvn; Bvc = Bvn; Cvc = Cvn;
  }
}

// K6a: merge 4 dirs + D*xs skip, LN over 192, *silu(z) -> yg (B,L,192). Wave per pixel.
__global__ void k_gate(const float* __restrict__ ys, const float* __restrict__ xc,
                       const float* __restrict__ Ds, const float* __restrict__ xz,
                       const float* __restrict__ ong, const float* __restrict__ onb,
                       float* __restrict__ yg){
  int gt = blockIdx.x*256 + threadIdx.x;
  int wave = gt >> 6;                // global pixel index (b*HW + l)
  int lane = gt & 63;
  int b = wave >> 12; int l = wave & (HW-1);
  int l1 = ((l & 63) << 6) | (l >> 6);
  size_t base = (size_t)b*KK*HW*DD;
  float v[3]; float s = 0.f, s2 = 0.f;
  #pragma unroll
  for (int j = 0; j < 3; ++j){
    int d = lane + j*64;
    float t;
    t  = ys[base + ((size_t)0*HW + l        )*DD + d];
    t += ys[base + ((size_t)1*HW + l1       )*DD + d];
    t += ys[base + ((size_t)2*HW + (HW-1-l ))*DD + d];
    t += ys[base + ((size_t)3*HW + (HW-1-l1))*DD + d];
    t += xc[((size_t)b*HW + l)*DD + d] * (Ds[d] + Ds[DD+d] + Ds[2*DD+d] + Ds[3*DD+d]);
    v[j] = t; s += t; s2 += t*t;
  }
  #pragma unroll
  for (int off = 32; off; off >>= 1){ s += __shfl_xor(s, off); s2 += __shfl_xor(s2, off); }
  float mu = s*(1.f/DD);
  float rstd = rsqrtf(s2*(1.f/DD) - mu*mu + 1e-5f);
  #pragma unroll
  for (int j = 0; j < 3; ++j){
    int d = lane + j*64;
    float z = xz[((size_t)b*HW + l)*384 + DD + d];
    float x = (v[j]-mu)*rstd*ong[d] + onb[d];
    yg[(size_t)wave*DD + d] = x * siluf(z);
  }
}

// K6b: out = yg(8192x192) @ opw^T(192x96), NCHW write. 32px x 96c per block.
__global__ void k_outproj(const float* __restrict__ yg, const float* __restrict__ opw,
                          float* __restrict__ out){
  __shared__ float yl[48][36];   // [k][px], pad
  __shared__ float wl[48][97];   // [k][c], pad
  int blk = blockIdx.x;          // b*128 + pt
  int b = blk >> 7; int pt = blk & 127;
  int px0 = pt*32;
  int tid = threadIdx.x;
  int pxg = tid & 7;             // 8 groups x 4 px
  int cgi = tid >> 3;            // 32 groups x 3 c
  float acc[4][3] = {};
  for (int k0 = 0; k0 < DD; k0 += 48){
    if (k0) __syncthreads();
    for (int i = tid; i < 32*48; i += 256){
      int r = i/48, k = i - r*48;
      yl[k][r] = yg[((size_t)b*HW + px0 + r)*DD + k0 + k];
    }
    for (int i = tid; i < 96*48; i += 256){
      int c = i/48, k = i - c*48;
      wl[k][c] = opw[(size_t)c*DD + k0 + k];
    }
    __syncthreads();
    #pragma unroll 4
    for (int k = 0; k < 48; ++k){
      float4 yv = *(const float4*)&yl[k][pxg*4];
      float w0 = wl[k][cgi*3], w1 = wl[k][cgi*3+1], w2 = wl[k][cgi*3+2];
      acc[0][0] += yv.x*w0; acc[0][1] += yv.x*w1; acc[0][2] += yv.x*w2;
      acc[1][0] += yv.y*w0; acc[1][1] += yv.y*w1; acc[1][2] += yv.y*w2;
      acc[2][0] += yv.z*w0; acc[2][1] += yv.z*w1; acc[2][2] += yv.z*w2;
      acc[3][0] += yv.w*w0; acc[3][1] += yv.w*w1; acc[3][2] += yv.w*w2;
    }
  }
  #pragma unroll
  for (int j = 0; j < 3; ++j){
    int c = cgi*3 + j;
    float4 o = {acc[0][j], acc[1][j], acc[2][j], acc[3][j]};
    *(float4*)&out[((size_t)b*CC + c)*HW + px0 + pxg*4] = o;
  }
}

extern "C" void kernel_launch(void* const* d_in, const int* in_sizes, int n_in,
                              void* d_out, int out_size, void* d_ws, size_t ws_size,
                              hipStream_t stream) {
  const float* rgb   = (const float*)d_in[0];
  const float* tt    = (const float*)d_in[1];
  const float* cw    = (const float*)d_in[2];
  const float* cb    = (const float*)d_in[3];
  const float* bng   = (const float*)d_in[4];
  const float* bnb   = (const float*)d_in[5];
  const float* bnm   = (const float*)d_in[6];
  const float* bnv   = (const float*)d_in[7];
  const float* lng   = (const float*)d_in[8];
  const float* lnb   = (const float*)d_in[9];
  const float* ipw   = (const float*)d_in[10];
  const float* dww   = (const float*)d_in[11];
  const float* dwb   = (const float*)d_in[12];
  const float* xpw   = (const float*)d_in[13];
  const float* dtw   = (const float*)d_in[14];
  const float* dtb   = (const float*)d_in[15];
  const float* Alog  = (const float*)d_in[16];
  const float* Ds    = (const float*)d_in[17];
  const float* ong   = (const float*)d_in[18];
  const float* onb   = (const float*)d_in[19];
  const float* opw   = (const float*)d_in[20];
  float* out = (float*)d_out;

  float* ws = (float*)d_ws;
  // persistent regions:
  float* xn   = ws + 786432;                 // 786432 (pixel-major, post-LN)
  float* xz   = ws + 1572864;                // 3145728
  float* xc   = ws + 4718592;                // 1572864
  float* Bsb  = ws + 6291456;                // 524288
  float* Csb  = ws + 6815744;                // 524288
  float* dlt  = ws + 7340032;                // 6291456
  float* ysb  = ws + 13631488;               // 6291456  (end 19922944 floats ~76MB)
  // transient overlays:
  float* pbuf = ws + 1572864;                // 6291456 (xz..dlt-front; dead before k_inproj)
  float* Ac   = ws;                          // 1572864 (conv/xn region; xn dead after inproj)
  float* Bc   = ysb;                         // 1572864 (front of ysb; dead before k_scan3 writes ys)
  float* yg   = ws + 7340032;                // 1572864 (over dlt; dlt dead after k_scan3)
  // k_scan2 writes hst in-place over Ac; k_scan3 reads it from there.

  k_conv1<<<256, 512, 0, stream>>>(rgb, tt, cw, pbuf);
  k_convred<<<4096, 256, 0, stream>>>(pbuf, cb, bng, bnb, bnm, bnv, lng, lnb, xn);
  dim3 g2(128, 6);
  k_inproj<<<g2, 256, 0, stream>>>(xn, ipw, xz);
  k_dwconv<<<6144, 256, 0, stream>>>(xz, dww, dwb, xc);
  k_xdbl<<<512, 192, 0, stream>>>(xc, xpw, dtw, dtb, Bsb, Csb, dlt);
  k_scan1<<<1536, 256, 0, stream>>>(dlt, xc, Bsb, Alog, Ac, Bc);
  k_scan2<<<96, 256, 0, stream>>>(Ac, Bc);
  k_scan3<<<1536, 256, 0, stream>>>(dlt, xc, Bsb, Csb, Alog, Ac, ysb);
  k_gate<<<2048, 256, 0, stream>>>(ysb, xc, Ds, xz, ong, onb, yg);
  k_outproj<<<256, 256, 0, stream>>>(yg, opw, out);
}